// Round 3
// baseline (1797.413 us; speedup 1.0000x reference)
//
#include <hip/hip_runtime.h>

#define BB 4
#define VV 50000
#define CC 128
#define KK 128
#define EE 400000
#define HH 128

#define CHUNK 512
#define NCHUNK 98        // ceil(VV/CHUNK)
#define PROJ_NCH 256     // v-chunks per batch; 1024 blocks total = 4/CU
#define TILES_PER_B 1563 // ceil(VV/32)  (unproject)
#define NT64 782         // ceil(VV/64)  (gradfeat / mlp)

typedef unsigned short u16;
typedef short bf16x8 __attribute__((ext_vector_type(8)));
typedef float f32x4 __attribute__((ext_vector_type(4)));

__device__ __forceinline__ u16 f2bf(float f) {
    union { float f; unsigned u; } x; x.f = f;
    unsigned r = x.u + 0x7FFFu + ((x.u >> 16) & 1u);
    return (u16)(r >> 16);
}
__device__ __forceinline__ float bf2f(u16 u) {
    union { unsigned u; float f; } x; x.u = ((unsigned)u) << 16;
    return x.f;
}
__device__ __forceinline__ unsigned pack2(float lo, float hi) {
    return ((unsigned)f2bf(hi) << 16) | (unsigned)f2bf(lo);
}
__device__ __forceinline__ float tanh_fast(float u) {
    float uc = fminf(fmaxf(u, -15.f), 15.f);
    float e = __expf(-2.f * uc);
    return (1.f - e) / (1.f + e);
}

// ---------------- utility ----------------
__global__ void k_zero_u32(unsigned int* __restrict__ p, int n) {
    int i = blockIdx.x * blockDim.x + threadIdx.x;
    if (i < n) p[i] = 0u;
}

// ---------------- edge bucketing (counting sort by row) ----------------
__global__ void k_hist(const int* __restrict__ rows, int* __restrict__ hist) {
    int idx = blockIdx.x * blockDim.x + threadIdx.x;
    if (idx >= BB * EE) return;
    int b = idx / EE;
    atomicAdd(&hist[b * VV + rows[idx]], 1);
}

__global__ void k_scan1(const int* __restrict__ hist, int* __restrict__ rs,
                        int* __restrict__ csum) {
    int t = threadIdx.x;
    if (t >= BB * NCHUNK) return;
    int b = t / NCHUNK, ch = t % NCHUNK;
    int base = ch * CHUNK;
    int sum = 0;
    for (int i = 0; i < CHUNK; ++i) {
        int v = base + i;
        if (v >= VV) break;
        int h = hist[b * VV + v];
        rs[b * VV + v] = sum;
        sum += h;
    }
    csum[b * 128 + ch] = sum;
}

__global__ void k_scan2(int* __restrict__ csum) {
    int b = threadIdx.x;
    if (b >= BB) return;
    int run = 0;
    for (int ch = 0; ch < NCHUNK; ++ch) {
        int t = csum[b * 128 + ch];
        csum[b * 128 + ch] = run;
        run += t;
    }
}

__global__ void k_scan3(int* __restrict__ rs, const int* __restrict__ csum,
                        int* __restrict__ cursor) {
    int idx = blockIdx.x * blockDim.x + threadIdx.x;
    if (idx >= BB * VV) return;
    int b = idx / VV, v = idx % VV;
    int r = rs[idx] + csum[b * 128 + v / CHUNK];
    rs[idx] = r;
    cursor[idx] = r;
}

__global__ void k_bucket(const int* __restrict__ rows, int* __restrict__ cursor,
                         int* __restrict__ edge_idx) {
    int idx = blockIdx.x * blockDim.x + threadIdx.x;
    if (idx >= BB * EE) return;
    int b = idx / EE, e = idx % EE;
    int r = rows[idx];
    int p = atomicAdd(&cursor[b * VV + r], 1);
    edge_idx[(size_t)b * EE + p] = e;
}

// ---------------- weight packing into MFMA B-fragment order ----------------
// B-frag layout (16x16x32): lane holds B[k = s*32 + (lane>>4)*8 + j][n = t*16 + (lane&15)]
// packed index: ((t*S + s)*64 + lane)*8 + j
__global__ void k_pack_rot(const float* __restrict__ Are, const float* __restrict__ Aim,
                           u16* __restrict__ Wre_p, u16* __restrict__ Wim_p) {
    int f = blockIdx.x * blockDim.x + threadIdx.x;  // 8t*8s*64 = 4096
    if (f >= 4096) return;
    int lane = f & 63;
    int s = (f >> 6) & 7;
    int t = f >> 9;
    int n = t * 16 + (lane & 15);
#pragma unroll
    for (int j = 0; j < 8; ++j) {
        int k = s * 32 + ((lane >> 4) << 3) + j;
        float re, im;
        if (k < 128) { re = Are[k * CC + n];           im = Aim[k * CC + n]; }
        else         { re = -Aim[(k - 128) * CC + n];  im = Are[(k - 128) * CC + n]; }
        Wre_p[(size_t)f * 8 + j] = f2bf(re);
        Wim_p[(size_t)f * 8 + j] = f2bf(im);
    }
}

__global__ void k_pack_w0(const float* __restrict__ W0, u16* __restrict__ W0p) {
    int f = blockIdx.x * blockDim.x + threadIdx.x;  // 8t*12s*64 = 6144
    if (f >= 6144) return;
    int lane = f & 63;
    int rem = f % 768;
    int s = rem >> 6;
    int t = f / 768;
    int n = t * 16 + (lane & 15);
#pragma unroll
    for (int j = 0; j < 8; ++j) {
        int k = s * 32 + ((lane >> 4) << 3) + j;
        W0p[(size_t)f * 8 + j] = f2bf(W0[(size_t)k * HH + n]);
    }
}

__global__ void k_pack_w1(const float* __restrict__ W1, u16* __restrict__ W1p) {
    int f = blockIdx.x * blockDim.x + threadIdx.x;  // 8t*4s*64 = 2048
    if (f >= 2048) return;
    int lane = f & 63;
    int s = (f >> 6) & 3;
    int t = f >> 8;
    int n = t * 16 + (lane & 15);
#pragma unroll
    for (int j = 0; j < 8; ++j) {
        int k = s * 32 + ((lane >> 4) << 3) + j;
        W1p[(size_t)f * 8 + j] = f2bf(W1[(size_t)k * CC + n]);
    }
}

// ---------------- stage A: spectral projection (fp32 vector) ----------------
// Wave-autonomous, barrier-free: each wave owns k-range [w*32, w*32+32) x full C,
// stages its own 4-row groups in wave-private double-buffered LDS, syncs only
// via lgkmcnt (wave-synchronous). Global loads for group g+1 issued before the
// compute of group g so latency hides under FMA work instead of a barrier drain.
__global__ __launch_bounds__(256, 4) void k_project(
        const float* __restrict__ x_in, const float* __restrict__ mass,
        const float* __restrict__ evecs, float* __restrict__ spec) {
    __shared__ float xs[4][2][4][128];  // [wave][buf][row][c]
    __shared__ float es[4][2][4][34];   // [wave][buf][row][k'] (mass folded), padded
    int b  = blockIdx.x / PROJ_NCH;
    int ch = blockIdx.x % PROJ_NCH;
    const int rowsPer = (VV + PROJ_NCH - 1) / PROJ_NCH;  // 196
    int vbase = ch * rowsPer;
    int vend  = min(vbase + rowsPer, VV);
    int t = threadIdx.x;
    int w = t >> 6, l = t & 63;
    int k0 = w * 32;
    int lk = l >> 4, lc = l & 15;   // compute-side tile coords

    // loader roles (all lanes participate)
    int xrow0 = (l >> 5) * 2;       // 0 or 2 -> this lane stages rows xrow0, xrow0+1
    int xc4   = (l & 31) * 4;       // float4 column
    int erow  = l >> 4;             // 0..3
    int ek2   = (l & 15) * 2;       // 0..30

    float acc[8][8];
#pragma unroll
    for (int a = 0; a < 8; ++a)
#pragma unroll
        for (int d = 0; d < 8; ++d) acc[a][d] = 0.f;

    int nG = (vend - vbase + 3) >> 2;

    float4 xA, xB; float2 E; float M;
    {   // prefetch group 0
        int v0 = vbase;
        int va = min(v0 + xrow0, vend - 1);
        int vb2 = min(v0 + xrow0 + 1, vend - 1);
        int ve = v0 + erow;
        int vec = min(ve, vend - 1);
        xA = *(const float4*)&x_in[((size_t)b * VV + va) * CC + xc4];
        xB = *(const float4*)&x_in[((size_t)b * VV + vb2) * CC + xc4];
        E  = *(const float2*)&evecs[((size_t)b * VV + vec) * KK + k0 + ek2];
        M  = (ve < vend) ? mass[b * VV + ve] : 0.f;
    }

    for (int g = 0; g < nG; ++g) {
        int buf = g & 1;
        // stage current group into wave-private LDS
        *(float4*)&xs[w][buf][xrow0][xc4]     = xA;
        *(float4*)&xs[w][buf][xrow0 + 1][xc4] = xB;
        *(float2*)&es[w][buf][erow][ek2] = make_float2(E.x * M, E.y * M);
        // issue next group's global loads (latency hides under compute below)
        if (g + 1 < nG) {
            int v0 = vbase + (g + 1) * 4;
            int va = min(v0 + xrow0, vend - 1);
            int vb2 = min(v0 + xrow0 + 1, vend - 1);
            int ve = v0 + erow;
            int vec = min(ve, vend - 1);
            xA = *(const float4*)&x_in[((size_t)b * VV + va) * CC + xc4];
            xB = *(const float4*)&x_in[((size_t)b * VV + vb2) * CC + xc4];
            E  = *(const float2*)&evecs[((size_t)b * VV + vec) * KK + k0 + ek2];
            M  = (ve < vend) ? mass[b * VV + ve] : 0.f;
        }
        // compute: 4 rows x (8k x 8c) FMAs per lane; wave-synchronous LDS reads
#pragma unroll
        for (int r = 0; r < 4; ++r) {
            float4 e0 = *(const float4*)&es[w][buf][r][lk * 4];
            float4 e1 = *(const float4*)&es[w][buf][r][16 + lk * 4];
            float4 x0 = *(const float4*)&xs[w][buf][r][lc * 4];
            float4 x1 = *(const float4*)&xs[w][buf][r][64 + lc * 4];
            float e[8] = {e0.x, e0.y, e0.z, e0.w, e1.x, e1.y, e1.z, e1.w};
            float x[8] = {x0.x, x0.y, x0.z, x0.w, x1.x, x1.y, x1.z, x1.w};
#pragma unroll
            for (int a = 0; a < 8; ++a)
#pragma unroll
                for (int d = 0; d < 8; ++d)
                    acc[a][d] = fmaf(e[a], x[d], acc[a][d]);
        }
    }

#pragma unroll
    for (int a = 0; a < 8; ++a) {
        int k = k0 + lk * 4 + (a & 3) + ((a >> 2) << 4);
#pragma unroll
        for (int d = 0; d < 8; ++d) {
            int c = lc * 4 + (d & 3) + ((d >> 2) << 6);
            atomicAdd(&spec[((size_t)b * KK + k) * CC + c], acc[a][d]);
        }
    }
}

// ---------------- stage B: spectral decay ----------------
__global__ void k_decay(const float* __restrict__ spec, const float* __restrict__ evals,
                        const float* __restrict__ dt, float* __restrict__ spec_d) {
    int idx = blockIdx.x * blockDim.x + threadIdx.x;
    if (idx >= BB * KK * CC) return;
    int c = idx & 127;
    int k = (idx >> 7) & 127;
    int b = idx >> 14;
    float t = fmaxf(dt[c], 1e-8f);
    spec_d[idx] = spec[idx] * expf(-evals[b * KK + k] * t);
}

// ---------------- stage C: unproject (fp32 compute, bf16 out) ----------------
__global__ __launch_bounds__(256) void k_unproject(
        const float* __restrict__ evecs, const float* __restrict__ spec_d,
        u16* __restrict__ xd) {
    __shared__ float ss[128][128];
    __shared__ float evs[32][128];
    int b = blockIdx.x / TILES_PER_B;
    int vbase = (blockIdx.x % TILES_PER_B) * 32;
    int t = threadIdx.x;

#pragma unroll
    for (int l = 0; l < 16; ++l) {
        int idx4 = l * 256 + t;
        int row = idx4 >> 5;
        int c4 = (idx4 & 31) * 4;
        *(float4*)&ss[row][c4] = *(const float4*)&spec_d[((size_t)b * KK + row) * CC + c4];
    }
#pragma unroll
    for (int l = 0; l < 4; ++l) {
        int idx4 = l * 256 + t;
        int row = idx4 >> 5;
        int c4 = (idx4 & 31) * 4;
        int v = vbase + row;
        float4 e4 = make_float4(0.f, 0.f, 0.f, 0.f);
        if (v < VV) e4 = *(const float4*)&evecs[((size_t)b * VV + v) * KK + c4];
        *(float4*)&evs[row][c4] = e4;
    }
    __syncthreads();

    int cg = t & 31, vg = t >> 5;
    int c4 = cg * 4;
    float acc[4][4];
#pragma unroll
    for (int i = 0; i < 4; ++i)
#pragma unroll
        for (int q = 0; q < 4; ++q) acc[i][q] = 0.f;

#pragma unroll 8
    for (int k = 0; k < 128; ++k) {
        float4 s = *(float4*)&ss[k][c4];
#pragma unroll
        for (int i = 0; i < 4; ++i) {
            float ev = evs[vg * 4 + i][k];
            acc[i][0] = fmaf(ev, s.x, acc[i][0]);
            acc[i][1] = fmaf(ev, s.y, acc[i][1]);
            acc[i][2] = fmaf(ev, s.z, acc[i][2]);
            acc[i][3] = fmaf(ev, s.w, acc[i][3]);
        }
    }
#pragma unroll
    for (int i = 0; i < 4; ++i) {
        int v = vbase + vg * 4 + i;
        if (v < VV) {
            uint2 o;
            o.x = pack2(acc[i][0], acc[i][1]);
            o.y = pack2(acc[i][2], acc[i][3]);
            *(uint2*)&xd[(((size_t)b * VV + v) << 7) + c4] = o;
        }
    }
}

// ---------------- stage D: row-gathered SpMM (bf16 xd -> bf16 gx,gy) -------
__global__ __launch_bounds__(256) void k_rowgather(
        const int* __restrict__ cols, const float* __restrict__ vxv,
        const float* __restrict__ vyv, const int* __restrict__ edge_idx,
        const int* __restrict__ rs, const int* __restrict__ cursor,
        const u16* __restrict__ xd, u16* __restrict__ gx, u16* __restrict__ gy) {
    int w = blockIdx.x * 4 + (threadIdx.x >> 6);
    int lane = threadIdx.x & 63;
    int b = w / VV;
    int beg = rs[w], end = cursor[w];
    float ax0 = 0.f, ax1 = 0.f, ay0 = 0.f, ay1 = 0.f;
    size_t ebase = (size_t)b * EE;
    for (int i = beg; i < end; ++i) {
        int e = edge_idx[ebase + i];
        int col = cols[ebase + e];
        float fx = vxv[ebase + e];
        float fy = vyv[ebase + e];
        unsigned u = *(const unsigned*)&xd[(((size_t)b * VV + col) << 7) + lane * 2];
        float x0 = bf2f((u16)(u & 0xFFFFu));
        float x1 = bf2f((u16)(u >> 16));
        ax0 = fmaf(fx, x0, ax0); ax1 = fmaf(fx, x1, ax1);
        ay0 = fmaf(fy, x0, ay0); ay1 = fmaf(fy, x1, ay1);
    }
    size_t ro = ((size_t)w << 7) + lane * 2;
    *(unsigned*)&gx[ro] = pack2(ax0, ax1);
    *(unsigned*)&gy[ro] = pack2(ay0, ay1);
}

// ---------------- stage E: spatial gradient features (MFMA bf16) -----------
__global__ __launch_bounds__(256) void k_gradfeat(
        const u16* __restrict__ gx, const u16* __restrict__ gy,
        const u16* __restrict__ Wre_p, const u16* __restrict__ Wim_p,
        u16* __restrict__ xgf) {
    __shared__ u16 Gs[64][264];     // [gx | gy] bf16, padded stride
    __shared__ u16 Bre[8][64][8];
    __shared__ u16 Bim[8][64][8];
    int b = blockIdx.x / NT64;
    int vbase = (blockIdx.x % NT64) * 64;
    int t = threadIdx.x;
    int lane = t & 63, w = t >> 6;
    {
        int row = t >> 2, p = t & 3;
        int v = vbase + row;
        bool ok = v < VV;
        size_t ro = ((size_t)b * VV + (ok ? v : 0)) << 7;
        const uint4* gxr = (const uint4*)&gx[ro + p * 32];
        const uint4* gyr = (const uint4*)&gy[ro + p * 32];
        uint4 z = make_uint4(0u, 0u, 0u, 0u);
#pragma unroll
        for (int i = 0; i < 4; ++i) {
            uint4 a = ok ? gxr[i] : z;
            uint4 c = ok ? gyr[i] : z;
            *(uint4*)&Gs[row][p * 32 + i * 8] = a;
            *(uint4*)&Gs[row][128 + p * 32 + i * 8] = c;
        }
    }
    __syncthreads();
    int m = lane & 15, q = lane >> 4;
    bf16x8 afr[8];
#pragma unroll
    for (int s = 0; s < 8; ++s)
        afr[s] = *(const bf16x8*)&Gs[w * 16 + m][s * 32 + q * 8];

    for (int tt = 0; tt < 8; ++tt) {
        __syncthreads();
        {
            const uint4* sre = (const uint4*)&Wre_p[(size_t)tt * 4096];
            const uint4* sim = (const uint4*)&Wim_p[(size_t)tt * 4096];
            uint4* dre = (uint4*)&Bre[0][0][0];
            uint4* dim = (uint4*)&Bim[0][0][0];
            dre[t] = sre[t]; dre[t + 256] = sre[t + 256];
            dim[t] = sim[t]; dim[t + 256] = sim[t + 256];
        }
        __syncthreads();
        f32x4 are = {0.f, 0.f, 0.f, 0.f};
        f32x4 aim = {0.f, 0.f, 0.f, 0.f};
#pragma unroll
        for (int s = 0; s < 8; ++s) {
            bf16x8 br = *(const bf16x8*)&Bre[s][lane][0];
            bf16x8 bi = *(const bf16x8*)&Bim[s][lane][0];
            are = __builtin_amdgcn_mfma_f32_16x16x32_bf16(afr[s], br, are, 0, 0, 0);
            aim = __builtin_amdgcn_mfma_f32_16x16x32_bf16(afr[s], bi, aim, 0, 0, 0);
        }
#pragma unroll
        for (int r = 0; r < 4; ++r) {
            int row = w * 16 + q * 4 + r;
            int v = vbase + row;
            if (v < VV) {
                float gxv = bf2f(Gs[row][tt * 16 + m]);
                float gyv = bf2f(Gs[row][128 + tt * 16 + m]);
                float u = gxv * are[r] + gyv * aim[r];
                xgf[(((size_t)b * VV + v) << 7) + tt * 16 + m] = f2bf(tanh_fast(u));
            }
        }
    }
}

// ---------------- stage F: fused MLP + residual (MFMA bf16) ----------------
__global__ __launch_bounds__(256) void k_mlp(
        const float* __restrict__ x_in, const u16* __restrict__ xd,
        const u16* __restrict__ xgf,
        const u16* __restrict__ W0p, const float* __restrict__ b0,
        const u16* __restrict__ W1p, const float* __restrict__ b1,
        float* __restrict__ out) {
    __shared__ u16 Fs[64][392];     // [x_in | xd | xgf] bf16, padded stride
    __shared__ u16 Hs[64][136];     // hidden, padded stride
    __shared__ u16 Bs[12][64][8];
    int b = blockIdx.x / NT64;
    int vbase = (blockIdx.x % NT64) * 64;
    int t = threadIdx.x;
    int lane = t & 63, w = t >> 6;
    {
        int row = t >> 2, p = t & 3;
        int v = vbase + row;
        bool ok = v < VV;
        size_t ro = ((size_t)b * VV + (ok ? v : 0)) << 7;
        const float4* xir = (const float4*)&x_in[ro + p * 32];
#pragma unroll
        for (int i = 0; i < 8; ++i) {
            float4 f = ok ? xir[i] : make_float4(0.f, 0.f, 0.f, 0.f);
            uint2 u;
            u.x = pack2(f.x, f.y);
            u.y = pack2(f.z, f.w);
            *(uint2*)&Fs[row][p * 32 + i * 4] = u;
        }
        const uint4* xdr = (const uint4*)&xd[ro + p * 32];
        const uint4* xgr = (const uint4*)&xgf[ro + p * 32];
        uint4 z = make_uint4(0u, 0u, 0u, 0u);
#pragma unroll
        for (int i = 0; i < 4; ++i) {
            uint4 a = ok ? xdr[i] : z;
            uint4 c = ok ? xgr[i] : z;
            *(uint4*)&Fs[row][128 + p * 32 + i * 8] = a;
            *(uint4*)&Fs[row][256 + p * 32 + i * 8] = c;
        }
    }
    __syncthreads();
    int m = lane & 15, q = lane >> 4;
    bf16x8 af[12];
#pragma unroll
    for (int s = 0; s < 12; ++s)
        af[s] = *(const bf16x8*)&Fs[w * 16 + m][s * 32 + q * 8];

    // GEMM1: feat @ W0 + b0 -> relu -> Hs
    for (int tt = 0; tt < 8; ++tt) {
        __syncthreads();
        {
            const uint4* src = (const uint4*)&W0p[(size_t)tt * 6144];
            uint4* d = (uint4*)&Bs[0][0][0];
            d[t] = src[t];
            d[t + 256] = src[t + 256];
            d[t + 512] = src[t + 512];
        }
        __syncthreads();
        f32x4 acc = {0.f, 0.f, 0.f, 0.f};
#pragma unroll
        for (int s = 0; s < 12; ++s) {
            bf16x8 bb = *(const bf16x8*)&Bs[s][lane][0];
            acc = __builtin_amdgcn_mfma_f32_16x16x32_bf16(af[s], bb, acc, 0, 0, 0);
        }
        float bias = b0[tt * 16 + m];
#pragma unroll
        for (int r = 0; r < 4; ++r) {
            Hs[w * 16 + q * 4 + r][tt * 16 + m] = f2bf(fmaxf(acc[r] + bias, 0.f));
        }
    }

    // GEMM2: h @ W1 + b1 + x_in -> out (A-frags from own wave's Hs rows)
    bf16x8 ah[4];
    for (int tt = 0; tt < 8; ++tt) {
        __syncthreads();
        {
            const uint4* src = (const uint4*)&W1p[(size_t)tt * 2048];
            uint4* d = (uint4*)&Bs[0][0][0];
            d[t] = src[t];
        }
        if (tt == 0) {
#pragma unroll
            for (int s = 0; s < 4; ++s)
                ah[s] = *(const bf16x8*)&Hs[w * 16 + m][s * 32 + q * 8];
        }
        __syncthreads();
        f32x4 acc = {0.f, 0.f, 0.f, 0.f};
#pragma unroll
        for (int s = 0; s < 4; ++s) {
            bf16x8 bb = *(const bf16x8*)&Bs[s][lane][0];
            acc = __builtin_amdgcn_mfma_f32_16x16x32_bf16(ah[s], bb, acc, 0, 0, 0);
        }
        float bias = b1[tt * 16 + m];
#pragma unroll
        for (int r = 0; r < 4; ++r) {
            int row = w * 16 + q * 4 + r;
            int v = vbase + row;
            if (v < VV) {
                size_t off = (((size_t)b * VV + v) << 7) + tt * 16 + m;
                out[off] = acc[r] + bias + x_in[off];
            }
        }
    }
}

extern "C" void kernel_launch(void* const* d_in, const int* in_sizes, int n_in,
                              void* d_out, int out_size, void* d_ws, size_t ws_size,
                              hipStream_t stream) {
    (void)in_sizes; (void)n_in; (void)out_size; (void)ws_size;
    const float* x_in  = (const float*)d_in[0];
    const float* mass  = (const float*)d_in[1];
    const float* evals = (const float*)d_in[3];
    const float* evecs = (const float*)d_in[4];
    const int* grad_rows = (const int*)d_in[5];
    const int* grad_cols = (const int*)d_in[6];
    const float* gX = (const float*)d_in[7];
    const float* gY = (const float*)d_in[8];
    const float* dt  = (const float*)d_in[9];
    const float* Are = (const float*)d_in[10];
    const float* Aim = (const float*)d_in[11];
    const float* W0 = (const float*)d_in[12];
    const float* b0 = (const float*)d_in[13];
    const float* W1 = (const float*)d_in[14];
    const float* b1 = (const float*)d_in[15];
    float* out = (float*)d_out;

    char* w = (char*)d_ws;
    u16* xd  = (u16*)w; w += (size_t)BB * VV * CC * 2;
    u16* gx  = (u16*)w; w += (size_t)BB * VV * CC * 2;
    u16* gy  = (u16*)w; w += (size_t)BB * VV * CC * 2;
    u16* xgf = (u16*)w; w += (size_t)BB * VV * CC * 2;
    float* spec   = (float*)w; w += (size_t)BB * KK * CC * 4;
    float* spec_d = (float*)w; w += (size_t)BB * KK * CC * 4;
    int* hist   = (int*)w; w += (size_t)BB * VV * 4;
    int* rs     = (int*)w; w += (size_t)BB * VV * 4;
    int* cursor = (int*)w; w += (size_t)BB * VV * 4;
    int* csum   = (int*)w; w += (size_t)BB * 128 * 4;
    int* edge_idx = (int*)w; w += (size_t)BB * EE * 4;
    u16* Wre_p = (u16*)w; w += (size_t)4096 * 8 * 2;
    u16* Wim_p = (u16*)w; w += (size_t)4096 * 8 * 2;
    u16* W0p   = (u16*)w; w += (size_t)6144 * 8 * 2;
    u16* W1p   = (u16*)w; w += (size_t)2048 * 8 * 2;

    hipLaunchKernelGGL(k_zero_u32, dim3((BB * VV + 255) / 256), dim3(256), 0, stream,
                       (unsigned int*)hist, BB * VV);
    hipLaunchKernelGGL(k_zero_u32, dim3((BB * KK * CC + 255) / 256), dim3(256), 0, stream,
                       (unsigned int*)spec, BB * KK * CC);
    hipLaunchKernelGGL(k_hist, dim3((BB * EE + 255) / 256), dim3(256), 0, stream,
                       grad_rows, hist);
    hipLaunchKernelGGL(k_scan1, dim3(1), dim3(512), 0, stream, hist, rs, csum);
    hipLaunchKernelGGL(k_scan2, dim3(1), dim3(64), 0, stream, csum);
    hipLaunchKernelGGL(k_scan3, dim3((BB * VV + 255) / 256), dim3(256), 0, stream,
                       rs, csum, cursor);
    hipLaunchKernelGGL(k_bucket, dim3((BB * EE + 255) / 256), dim3(256), 0, stream,
                       grad_rows, cursor, edge_idx);
    hipLaunchKernelGGL(k_pack_rot, dim3(16), dim3(256), 0, stream, Are, Aim, Wre_p, Wim_p);
    hipLaunchKernelGGL(k_pack_w0, dim3(24), dim3(256), 0, stream, W0, W0p);
    hipLaunchKernelGGL(k_pack_w1, dim3(8), dim3(256), 0, stream, W1, W1p);
    hipLaunchKernelGGL(k_project, dim3(BB * PROJ_NCH), dim3(256), 0, stream,
                       x_in, mass, evecs, spec);
    hipLaunchKernelGGL(k_decay, dim3((BB * KK * CC + 255) / 256), dim3(256), 0, stream,
                       spec, evals, dt, spec_d);
    hipLaunchKernelGGL(k_unproject, dim3(BB * TILES_PER_B), dim3(256), 0, stream,
                       evecs, spec_d, xd);
    hipLaunchKernelGGL(k_rowgather, dim3(BB * VV / 4), dim3(256), 0, stream,
                       grad_cols, gX, gY, edge_idx, rs, cursor, xd, gx, gy);
    hipLaunchKernelGGL(k_gradfeat, dim3(BB * NT64), dim3(256), 0, stream,
                       gx, gy, Wre_p, Wim_p, xgf);
    hipLaunchKernelGGL(k_mlp, dim3(BB * NT64), dim3(256), 0, stream,
                       x_in, xd, xgf, W0p, b0, W1p, b1, out);
}

// Round 4
// 1365.014 us; speedup vs baseline: 1.3168x; 1.3168x over previous
//
#include <hip/hip_runtime.h>

#define BB 4
#define VV 50000
#define CC 128
#define KK 128
#define EE 400000
#define HH 128

#define CHUNK 512
#define NCHUNK 98        // ceil(VV/CHUNK)
#define PROJ_NCH 64      // v-chunks per batch for k_project (512-thread blocks)
#define TILES_PER_B 1563 // ceil(VV/32)  (unproject)
#define NT64 782         // ceil(VV/64)  (gradfeat / mlp)

typedef unsigned short u16;
typedef short bf16x8 __attribute__((ext_vector_type(8)));
typedef float f32x4 __attribute__((ext_vector_type(4)));

__device__ __forceinline__ u16 f2bf(float f) {
    union { float f; unsigned u; } x; x.f = f;
    unsigned r = x.u + 0x7FFFu + ((x.u >> 16) & 1u);
    return (u16)(r >> 16);
}
__device__ __forceinline__ float bf2f(u16 u) {
    union { unsigned u; float f; } x; x.u = ((unsigned)u) << 16;
    return x.f;
}
__device__ __forceinline__ unsigned pack2(float lo, float hi) {
    return ((unsigned)f2bf(hi) << 16) | (unsigned)f2bf(lo);
}
__device__ __forceinline__ float tanh_fast(float u) {
    float uc = fminf(fmaxf(u, -15.f), 15.f);
    float e = __expf(-2.f * uc);
    return (1.f - e) / (1.f + e);
}
__device__ __forceinline__ f32x4 fma4(float s, float4 v, f32x4 a) {
    a.x = fmaf(s, v.x, a.x);
    a.y = fmaf(s, v.y, a.y);
    a.z = fmaf(s, v.z, a.z);
    a.w = fmaf(s, v.w, a.w);
    return a;
}

// ---------------- utility ----------------
__global__ void k_zero_u32(unsigned int* __restrict__ p, int n) {
    int i = blockIdx.x * blockDim.x + threadIdx.x;
    if (i < n) p[i] = 0u;
}

// ---------------- edge bucketing (counting sort by row) ----------------
__global__ void k_hist(const int* __restrict__ rows, int* __restrict__ hist) {
    int idx = blockIdx.x * blockDim.x + threadIdx.x;
    if (idx >= BB * EE) return;
    int b = idx / EE;
    atomicAdd(&hist[b * VV + rows[idx]], 1);
}

__global__ void k_scan1(const int* __restrict__ hist, int* __restrict__ rs,
                        int* __restrict__ csum) {
    int t = threadIdx.x;
    if (t >= BB * NCHUNK) return;
    int b = t / NCHUNK, ch = t % NCHUNK;
    int base = ch * CHUNK;
    int sum = 0;
    for (int i = 0; i < CHUNK; ++i) {
        int v = base + i;
        if (v >= VV) break;
        int h = hist[b * VV + v];
        rs[b * VV + v] = sum;
        sum += h;
    }
    csum[b * 128 + ch] = sum;
}

__global__ void k_scan2(int* __restrict__ csum) {
    int b = threadIdx.x;
    if (b >= BB) return;
    int run = 0;
    for (int ch = 0; ch < NCHUNK; ++ch) {
        int t = csum[b * 128 + ch];
        csum[b * 128 + ch] = run;
        run += t;
    }
}

__global__ void k_scan3(int* __restrict__ rs, const int* __restrict__ csum,
                        int* __restrict__ cursor) {
    int idx = blockIdx.x * blockDim.x + threadIdx.x;
    if (idx >= BB * VV) return;
    int b = idx / VV, v = idx % VV;
    int r = rs[idx] + csum[b * 128 + v / CHUNK];
    rs[idx] = r;
    cursor[idx] = r;
}

__global__ void k_bucket(const int* __restrict__ rows, int* __restrict__ cursor,
                         int* __restrict__ edge_idx) {
    int idx = blockIdx.x * blockDim.x + threadIdx.x;
    if (idx >= BB * EE) return;
    int b = idx / EE, e = idx % EE;
    int r = rows[idx];
    int p = atomicAdd(&cursor[b * VV + r], 1);
    edge_idx[(size_t)b * EE + p] = e;
}

// ---------------- weight packing into MFMA B-fragment order ----------------
// B-frag layout (16x16x32): lane holds B[k = s*32 + (lane>>4)*8 + j][n = t*16 + (lane&15)]
// packed index: ((t*S + s)*64 + lane)*8 + j
__global__ void k_pack_rot(const float* __restrict__ Are, const float* __restrict__ Aim,
                           u16* __restrict__ Wre_p, u16* __restrict__ Wim_p) {
    int f = blockIdx.x * blockDim.x + threadIdx.x;  // 8t*8s*64 = 4096
    if (f >= 4096) return;
    int lane = f & 63;
    int s = (f >> 6) & 7;
    int t = f >> 9;
    int n = t * 16 + (lane & 15);
#pragma unroll
    for (int j = 0; j < 8; ++j) {
        int k = s * 32 + ((lane >> 4) << 3) + j;
        float re, im;
        if (k < 128) { re = Are[k * CC + n];           im = Aim[k * CC + n]; }
        else         { re = -Aim[(k - 128) * CC + n];  im = Are[(k - 128) * CC + n]; }
        Wre_p[(size_t)f * 8 + j] = f2bf(re);
        Wim_p[(size_t)f * 8 + j] = f2bf(im);
    }
}

__global__ void k_pack_w0(const float* __restrict__ W0, u16* __restrict__ W0p) {
    int f = blockIdx.x * blockDim.x + threadIdx.x;  // 8t*12s*64 = 6144
    if (f >= 6144) return;
    int lane = f & 63;
    int rem = f % 768;
    int s = rem >> 6;
    int t = f / 768;
    int n = t * 16 + (lane & 15);
#pragma unroll
    for (int j = 0; j < 8; ++j) {
        int k = s * 32 + ((lane >> 4) << 3) + j;
        W0p[(size_t)f * 8 + j] = f2bf(W0[(size_t)k * HH + n]);
    }
}

__global__ void k_pack_w1(const float* __restrict__ W1, u16* __restrict__ W1p) {
    int f = blockIdx.x * blockDim.x + threadIdx.x;  // 8t*4s*64 = 2048
    if (f >= 2048) return;
    int lane = f & 63;
    int s = (f >> 6) & 3;
    int t = f >> 8;
    int n = t * 16 + (lane & 15);
#pragma unroll
    for (int j = 0; j < 8; ++j) {
        int k = s * 32 + ((lane >> 4) << 3) + j;
        W1p[(size_t)f * 8 + j] = f2bf(W1[(size_t)k * CC + n]);
    }
}

// ---------------- stage A: spectral projection (fp32 vector, de-spilled) ----
// 512 threads; thread (tk = t>>5, tc = t&31) owns k = tk*8+{0..7}, c = tc*4+{0..3}.
// Accumulator = 8 named f32x4 (32 VGPRs, statically indexed -> stays in registers;
// previous versions' acc[8][8] spilled to scratch: VGPR_Count was 52 < 64 accs).
// 16-row LDS tiles, register prefetch across the barrier (T14).
__global__ __launch_bounds__(512) void k_project(
        const float* __restrict__ x_in, const float* __restrict__ mass,
        const float* __restrict__ evecs, float* __restrict__ spec) {
    __shared__ float evs[16][128];
    __shared__ float xs[16][128];
    int b  = blockIdx.x >> 6;
    int ch = blockIdx.x & 63;
    const int rowsPer = (VV + PROJ_NCH - 1) / PROJ_NCH;  // 782
    int vbase = ch * rowsPer;
    int vend  = min(vbase + rowsPer, VV);
    int t = threadIdx.x;
    int tk = t >> 5, tc = t & 31;
    int lrow = tk;            // loader row 0..15 (32 threads per row)
    int lc4  = tc * 4;        // loader float4 column

    f32x4 a0 = {0,0,0,0}, a1 = {0,0,0,0}, a2 = {0,0,0,0}, a3 = {0,0,0,0};
    f32x4 a4 = {0,0,0,0}, a5 = {0,0,0,0}, a6 = {0,0,0,0}, a7 = {0,0,0,0};

    float4 xr = make_float4(0.f, 0.f, 0.f, 0.f);
    float4 er = make_float4(0.f, 0.f, 0.f, 0.f);
    float  mr = 0.f;
    {   // prefetch tile 0
        int v = vbase + lrow;
        if (v < vend) {
            xr = *(const float4*)&x_in[((size_t)b * VV + v) * CC + lc4];
            er = *(const float4*)&evecs[((size_t)b * VV + v) * KK + lc4];
            mr = mass[b * VV + v];
        }
    }

    for (int v0 = vbase; v0 < vend; v0 += 16) {
        __syncthreads();
        *(float4*)&xs[lrow][lc4]  = make_float4(xr.x * mr, xr.y * mr, xr.z * mr, xr.w * mr);
        *(float4*)&evs[lrow][lc4] = er;
        __syncthreads();
        if (v0 + 16 < vend) {   // prefetch next tile; latency hides under compute
            int v = v0 + 16 + lrow;
            if (v < vend) {
                xr = *(const float4*)&x_in[((size_t)b * VV + v) * CC + lc4];
                er = *(const float4*)&evecs[((size_t)b * VV + v) * KK + lc4];
                mr = mass[b * VV + v];
            } else {
                xr = make_float4(0.f, 0.f, 0.f, 0.f);
                er = make_float4(0.f, 0.f, 0.f, 0.f);
                mr = 0.f;
            }
        }
#pragma unroll
        for (int vv = 0; vv < 16; ++vv) {
            float4 xv = *(const float4*)&xs[vv][tc * 4];
            float4 ea = *(const float4*)&evs[vv][tk * 8];
            float4 eb = *(const float4*)&evs[vv][tk * 8 + 4];
            a0 = fma4(ea.x, xv, a0);
            a1 = fma4(ea.y, xv, a1);
            a2 = fma4(ea.z, xv, a2);
            a3 = fma4(ea.w, xv, a3);
            a4 = fma4(eb.x, xv, a4);
            a5 = fma4(eb.y, xv, a5);
            a6 = fma4(eb.z, xv, a6);
            a7 = fma4(eb.w, xv, a7);
        }
    }

    {
        size_t base = ((size_t)b * KK + tk * 8) * CC + tc * 4;
        float* p0 = &spec[base];
        atomicAdd(p0 + 0, a0.x); atomicAdd(p0 + 1, a0.y); atomicAdd(p0 + 2, a0.z); atomicAdd(p0 + 3, a0.w);
        float* p1 = p0 + CC;
        atomicAdd(p1 + 0, a1.x); atomicAdd(p1 + 1, a1.y); atomicAdd(p1 + 2, a1.z); atomicAdd(p1 + 3, a1.w);
        float* p2 = p0 + 2 * CC;
        atomicAdd(p2 + 0, a2.x); atomicAdd(p2 + 1, a2.y); atomicAdd(p2 + 2, a2.z); atomicAdd(p2 + 3, a2.w);
        float* p3 = p0 + 3 * CC;
        atomicAdd(p3 + 0, a3.x); atomicAdd(p3 + 1, a3.y); atomicAdd(p3 + 2, a3.z); atomicAdd(p3 + 3, a3.w);
        float* p4 = p0 + 4 * CC;
        atomicAdd(p4 + 0, a4.x); atomicAdd(p4 + 1, a4.y); atomicAdd(p4 + 2, a4.z); atomicAdd(p4 + 3, a4.w);
        float* p5 = p0 + 5 * CC;
        atomicAdd(p5 + 0, a5.x); atomicAdd(p5 + 1, a5.y); atomicAdd(p5 + 2, a5.z); atomicAdd(p5 + 3, a5.w);
        float* p6 = p0 + 6 * CC;
        atomicAdd(p6 + 0, a6.x); atomicAdd(p6 + 1, a6.y); atomicAdd(p6 + 2, a6.z); atomicAdd(p6 + 3, a6.w);
        float* p7 = p0 + 7 * CC;
        atomicAdd(p7 + 0, a7.x); atomicAdd(p7 + 1, a7.y); atomicAdd(p7 + 2, a7.z); atomicAdd(p7 + 3, a7.w);
    }
}

// ---------------- stage B: spectral decay ----------------
__global__ void k_decay(const float* __restrict__ spec, const float* __restrict__ evals,
                        const float* __restrict__ dt, float* __restrict__ spec_d) {
    int idx = blockIdx.x * blockDim.x + threadIdx.x;
    if (idx >= BB * KK * CC) return;
    int c = idx & 127;
    int k = (idx >> 7) & 127;
    int b = idx >> 14;
    float t = fmaxf(dt[c], 1e-8f);
    spec_d[idx] = spec[idx] * expf(-evals[b * KK + k] * t);
}

// ---------------- stage C: unproject (fp32 compute, bf16 out) ----------------
__global__ __launch_bounds__(256) void k_unproject(
        const float* __restrict__ evecs, const float* __restrict__ spec_d,
        u16* __restrict__ xd) {
    __shared__ float ss[128][128];
    __shared__ float evs[32][128];
    int b = blockIdx.x / TILES_PER_B;
    int vbase = (blockIdx.x % TILES_PER_B) * 32;
    int t = threadIdx.x;

#pragma unroll
    for (int l = 0; l < 16; ++l) {
        int idx4 = l * 256 + t;
        int row = idx4 >> 5;
        int c4 = (idx4 & 31) * 4;
        *(float4*)&ss[row][c4] = *(const float4*)&spec_d[((size_t)b * KK + row) * CC + c4];
    }
#pragma unroll
    for (int l = 0; l < 4; ++l) {
        int idx4 = l * 256 + t;
        int row = idx4 >> 5;
        int c4 = (idx4 & 31) * 4;
        int v = vbase + row;
        float4 e4 = make_float4(0.f, 0.f, 0.f, 0.f);
        if (v < VV) e4 = *(const float4*)&evecs[((size_t)b * VV + v) * KK + c4];
        *(float4*)&evs[row][c4] = e4;
    }
    __syncthreads();

    int cg = t & 31, vg = t >> 5;
    int c4 = cg * 4;
    float acc[4][4];
#pragma unroll
    for (int i = 0; i < 4; ++i)
#pragma unroll
        for (int q = 0; q < 4; ++q) acc[i][q] = 0.f;

#pragma unroll 8
    for (int k = 0; k < 128; ++k) {
        float4 s = *(float4*)&ss[k][c4];
#pragma unroll
        for (int i = 0; i < 4; ++i) {
            float ev = evs[vg * 4 + i][k];
            acc[i][0] = fmaf(ev, s.x, acc[i][0]);
            acc[i][1] = fmaf(ev, s.y, acc[i][1]);
            acc[i][2] = fmaf(ev, s.z, acc[i][2]);
            acc[i][3] = fmaf(ev, s.w, acc[i][3]);
        }
    }
#pragma unroll
    for (int i = 0; i < 4; ++i) {
        int v = vbase + vg * 4 + i;
        if (v < VV) {
            uint2 o;
            o.x = pack2(acc[i][0], acc[i][1]);
            o.y = pack2(acc[i][2], acc[i][3]);
            *(uint2*)&xd[(((size_t)b * VV + v) << 7) + c4] = o;
        }
    }
}

// ---------------- stage D: row-gathered SpMM (bf16 xd -> bf16 gx,gy) -------
__global__ __launch_bounds__(256) void k_rowgather(
        const int* __restrict__ cols, const float* __restrict__ vxv,
        const float* __restrict__ vyv, const int* __restrict__ edge_idx,
        const int* __restrict__ rs, const int* __restrict__ cursor,
        const u16* __restrict__ xd, u16* __restrict__ gx, u16* __restrict__ gy) {
    int w = blockIdx.x * 4 + (threadIdx.x >> 6);
    int lane = threadIdx.x & 63;
    int b = w / VV;
    int beg = rs[w], end = cursor[w];
    float ax0 = 0.f, ax1 = 0.f, ay0 = 0.f, ay1 = 0.f;
    size_t ebase = (size_t)b * EE;
    for (int i = beg; i < end; ++i) {
        int e = edge_idx[ebase + i];
        int col = cols[ebase + e];
        float fx = vxv[ebase + e];
        float fy = vyv[ebase + e];
        unsigned u = *(const unsigned*)&xd[(((size_t)b * VV + col) << 7) + lane * 2];
        float x0 = bf2f((u16)(u & 0xFFFFu));
        float x1 = bf2f((u16)(u >> 16));
        ax0 = fmaf(fx, x0, ax0); ax1 = fmaf(fx, x1, ax1);
        ay0 = fmaf(fy, x0, ay0); ay1 = fmaf(fy, x1, ay1);
    }
    size_t ro = ((size_t)w << 7) + lane * 2;
    *(unsigned*)&gx[ro] = pack2(ax0, ax1);
    *(unsigned*)&gy[ro] = pack2(ay0, ay1);
}

// ---------------- stage E: spatial gradient features (MFMA bf16) -----------
__global__ __launch_bounds__(256) void k_gradfeat(
        const u16* __restrict__ gx, const u16* __restrict__ gy,
        const u16* __restrict__ Wre_p, const u16* __restrict__ Wim_p,
        u16* __restrict__ xgf) {
    __shared__ u16 Gs[64][264];     // [gx | gy] bf16, padded stride
    __shared__ u16 Bre[8][64][8];
    __shared__ u16 Bim[8][64][8];
    int b = blockIdx.x / NT64;
    int vbase = (blockIdx.x % NT64) * 64;
    int t = threadIdx.x;
    int lane = t & 63, w = t >> 6;
    {
        int row = t >> 2, p = t & 3;
        int v = vbase + row;
        bool ok = v < VV;
        size_t ro = ((size_t)b * VV + (ok ? v : 0)) << 7;
        const uint4* gxr = (const uint4*)&gx[ro + p * 32];
        const uint4* gyr = (const uint4*)&gy[ro + p * 32];
        uint4 z = make_uint4(0u, 0u, 0u, 0u);
#pragma unroll
        for (int i = 0; i < 4; ++i) {
            uint4 a = ok ? gxr[i] : z;
            uint4 c = ok ? gyr[i] : z;
            *(uint4*)&Gs[row][p * 32 + i * 8] = a;
            *(uint4*)&Gs[row][128 + p * 32 + i * 8] = c;
        }
    }
    __syncthreads();
    int m = lane & 15, q = lane >> 4;
    bf16x8 afr[8];
#pragma unroll
    for (int s = 0; s < 8; ++s)
        afr[s] = *(const bf16x8*)&Gs[w * 16 + m][s * 32 + q * 8];

    for (int tt = 0; tt < 8; ++tt) {
        __syncthreads();
        {
            const uint4* sre = (const uint4*)&Wre_p[(size_t)tt * 4096];
            const uint4* sim = (const uint4*)&Wim_p[(size_t)tt * 4096];
            uint4* dre = (uint4*)&Bre[0][0][0];
            uint4* dim = (uint4*)&Bim[0][0][0];
            dre[t] = sre[t]; dre[t + 256] = sre[t + 256];
            dim[t] = sim[t]; dim[t + 256] = sim[t + 256];
        }
        __syncthreads();
        f32x4 are = {0.f, 0.f, 0.f, 0.f};
        f32x4 aim = {0.f, 0.f, 0.f, 0.f};
#pragma unroll
        for (int s = 0; s < 8; ++s) {
            bf16x8 br = *(const bf16x8*)&Bre[s][lane][0];
            bf16x8 bi = *(const bf16x8*)&Bim[s][lane][0];
            are = __builtin_amdgcn_mfma_f32_16x16x32_bf16(afr[s], br, are, 0, 0, 0);
            aim = __builtin_amdgcn_mfma_f32_16x16x32_bf16(afr[s], bi, aim, 0, 0, 0);
        }
#pragma unroll
        for (int r = 0; r < 4; ++r) {
            int row = w * 16 + q * 4 + r;
            int v = vbase + row;
            if (v < VV) {
                float gxv = bf2f(Gs[row][tt * 16 + m]);
                float gyv = bf2f(Gs[row][128 + tt * 16 + m]);
                float u = gxv * are[r] + gyv * aim[r];
                xgf[(((size_t)b * VV + v) << 7) + tt * 16 + m] = f2bf(tanh_fast(u));
            }
        }
    }
}

// ---------------- stage F: fused MLP + residual (MFMA bf16) ----------------
__global__ __launch_bounds__(256) void k_mlp(
        const float* __restrict__ x_in, const u16* __restrict__ xd,
        const u16* __restrict__ xgf,
        const u16* __restrict__ W0p, const float* __restrict__ b0,
        const u16* __restrict__ W1p, const float* __restrict__ b1,
        float* __restrict__ out) {
    __shared__ u16 Fs[64][392];     // [x_in | xd | xgf] bf16, padded stride
    __shared__ u16 Hs[64][136];     // hidden, padded stride
    __shared__ u16 Bs[12][64][8];
    int b = blockIdx.x / NT64;
    int vbase = (blockIdx.x % NT64) * 64;
    int t = threadIdx.x;
    int lane = t & 63, w = t >> 6;
    {
        int row = t >> 2, p = t & 3;
        int v = vbase + row;
        bool ok = v < VV;
        size_t ro = ((size_t)b * VV + (ok ? v : 0)) << 7;
        const float4* xir = (const float4*)&x_in[ro + p * 32];
#pragma unroll
        for (int i = 0; i < 8; ++i) {
            float4 f = ok ? xir[i] : make_float4(0.f, 0.f, 0.f, 0.f);
            uint2 u;
            u.x = pack2(f.x, f.y);
            u.y = pack2(f.z, f.w);
            *(uint2*)&Fs[row][p * 32 + i * 4] = u;
        }
        const uint4* xdr = (const uint4*)&xd[ro + p * 32];
        const uint4* xgr = (const uint4*)&xgf[ro + p * 32];
        uint4 z = make_uint4(0u, 0u, 0u, 0u);
#pragma unroll
        for (int i = 0; i < 4; ++i) {
            uint4 a = ok ? xdr[i] : z;
            uint4 c = ok ? xgr[i] : z;
            *(uint4*)&Fs[row][128 + p * 32 + i * 8] = a;
            *(uint4*)&Fs[row][256 + p * 32 + i * 8] = c;
        }
    }
    __syncthreads();
    int m = lane & 15, q = lane >> 4;
    bf16x8 af[12];
#pragma unroll
    for (int s = 0; s < 12; ++s)
        af[s] = *(const bf16x8*)&Fs[w * 16 + m][s * 32 + q * 8];

    // GEMM1: feat @ W0 + b0 -> relu -> Hs
    for (int tt = 0; tt < 8; ++tt) {
        __syncthreads();
        {
            const uint4* src = (const uint4*)&W0p[(size_t)tt * 6144];
            uint4* d = (uint4*)&Bs[0][0][0];
            d[t] = src[t];
            d[t + 256] = src[t + 256];
            d[t + 512] = src[t + 512];
        }
        __syncthreads();
        f32x4 acc = {0.f, 0.f, 0.f, 0.f};
#pragma unroll
        for (int s = 0; s < 12; ++s) {
            bf16x8 bb = *(const bf16x8*)&Bs[s][lane][0];
            acc = __builtin_amdgcn_mfma_f32_16x16x32_bf16(af[s], bb, acc, 0, 0, 0);
        }
        float bias = b0[tt * 16 + m];
#pragma unroll
        for (int r = 0; r < 4; ++r) {
            Hs[w * 16 + q * 4 + r][tt * 16 + m] = f2bf(fmaxf(acc[r] + bias, 0.f));
        }
    }

    // GEMM2: h @ W1 + b1 + x_in -> out (A-frags from own wave's Hs rows)
    bf16x8 ah[4];
    for (int tt = 0; tt < 8; ++tt) {
        __syncthreads();
        {
            const uint4* src = (const uint4*)&W1p[(size_t)tt * 2048];
            uint4* d = (uint4*)&Bs[0][0][0];
            d[t] = src[t];
        }
        if (tt == 0) {
#pragma unroll
            for (int s = 0; s < 4; ++s)
                ah[s] = *(const bf16x8*)&Hs[w * 16 + m][s * 32 + q * 8];
        }
        __syncthreads();
        f32x4 acc = {0.f, 0.f, 0.f, 0.f};
#pragma unroll
        for (int s = 0; s < 4; ++s) {
            bf16x8 bb = *(const bf16x8*)&Bs[s][lane][0];
            acc = __builtin_amdgcn_mfma_f32_16x16x32_bf16(ah[s], bb, acc, 0, 0, 0);
        }
        float bias = b1[tt * 16 + m];
#pragma unroll
        for (int r = 0; r < 4; ++r) {
            int row = w * 16 + q * 4 + r;
            int v = vbase + row;
            if (v < VV) {
                size_t off = (((size_t)b * VV + v) << 7) + tt * 16 + m;
                out[off] = acc[r] + bias + x_in[off];
            }
        }
    }
}

extern "C" void kernel_launch(void* const* d_in, const int* in_sizes, int n_in,
                              void* d_out, int out_size, void* d_ws, size_t ws_size,
                              hipStream_t stream) {
    (void)in_sizes; (void)n_in; (void)out_size; (void)ws_size;
    const float* x_in  = (const float*)d_in[0];
    const float* mass  = (const float*)d_in[1];
    const float* evals = (const float*)d_in[3];
    const float* evecs = (const float*)d_in[4];
    const int* grad_rows = (const int*)d_in[5];
    const int* grad_cols = (const int*)d_in[6];
    const float* gX = (const float*)d_in[7];
    const float* gY = (const float*)d_in[8];
    const float* dt  = (const float*)d_in[9];
    const float* Are = (const float*)d_in[10];
    const float* Aim = (const float*)d_in[11];
    const float* W0 = (const float*)d_in[12];
    const float* b0 = (const float*)d_in[13];
    const float* W1 = (const float*)d_in[14];
    const float* b1 = (const float*)d_in[15];
    float* out = (float*)d_out;

    char* w = (char*)d_ws;
    u16* xd  = (u16*)w; w += (size_t)BB * VV * CC * 2;
    u16* gx  = (u16*)w; w += (size_t)BB * VV * CC * 2;
    u16* gy  = (u16*)w; w += (size_t)BB * VV * CC * 2;
    u16* xgf = (u16*)w; w += (size_t)BB * VV * CC * 2;
    float* spec   = (float*)w; w += (size_t)BB * KK * CC * 4;
    float* spec_d = (float*)w; w += (size_t)BB * KK * CC * 4;
    int* hist   = (int*)w; w += (size_t)BB * VV * 4;
    int* rs     = (int*)w; w += (size_t)BB * VV * 4;
    int* cursor = (int*)w; w += (size_t)BB * VV * 4;
    int* csum   = (int*)w; w += (size_t)BB * 128 * 4;
    int* edge_idx = (int*)w; w += (size_t)BB * EE * 4;
    u16* Wre_p = (u16*)w; w += (size_t)4096 * 8 * 2;
    u16* Wim_p = (u16*)w; w += (size_t)4096 * 8 * 2;
    u16* W0p   = (u16*)w; w += (size_t)6144 * 8 * 2;
    u16* W1p   = (u16*)w; w += (size_t)2048 * 8 * 2;

    hipLaunchKernelGGL(k_zero_u32, dim3((BB * VV + 255) / 256), dim3(256), 0, stream,
                       (unsigned int*)hist, BB * VV);
    hipLaunchKernelGGL(k_zero_u32, dim3((BB * KK * CC + 255) / 256), dim3(256), 0, stream,
                       (unsigned int*)spec, BB * KK * CC);
    hipLaunchKernelGGL(k_hist, dim3((BB * EE + 255) / 256), dim3(256), 0, stream,
                       grad_rows, hist);
    hipLaunchKernelGGL(k_scan1, dim3(1), dim3(512), 0, stream, hist, rs, csum);
    hipLaunchKernelGGL(k_scan2, dim3(1), dim3(64), 0, stream, csum);
    hipLaunchKernelGGL(k_scan3, dim3((BB * VV + 255) / 256), dim3(256), 0, stream,
                       rs, csum, cursor);
    hipLaunchKernelGGL(k_bucket, dim3((BB * EE + 255) / 256), dim3(256), 0, stream,
                       grad_rows, cursor, edge_idx);
    hipLaunchKernelGGL(k_pack_rot, dim3(16), dim3(256), 0, stream, Are, Aim, Wre_p, Wim_p);
    hipLaunchKernelGGL(k_pack_w0, dim3(24), dim3(256), 0, stream, W0, W0p);
    hipLaunchKernelGGL(k_pack_w1, dim3(8), dim3(256), 0, stream, W1, W1p);
    hipLaunchKernelGGL(k_project, dim3(BB * PROJ_NCH), dim3(512), 0, stream,
                       x_in, mass, evecs, spec);
    hipLaunchKernelGGL(k_decay, dim3((BB * KK * CC + 255) / 256), dim3(256), 0, stream,
                       spec, evals, dt, spec_d);
    hipLaunchKernelGGL(k_unproject, dim3(BB * TILES_PER_B), dim3(256), 0, stream,
                       evecs, spec_d, xd);
    hipLaunchKernelGGL(k_rowgather, dim3(BB * VV / 4), dim3(256), 0, stream,
                       grad_cols, gX, gY, edge_idx, rs, cursor, xd, gx, gy);
    hipLaunchKernelGGL(k_gradfeat, dim3(BB * NT64), dim3(256), 0, stream,
                       gx, gy, Wre_p, Wim_p, xgf);
    hipLaunchKernelGGL(k_mlp, dim3(BB * NT64), dim3(256), 0, stream,
                       x_in, xd, xgf, W0p, b0, W1p, b1, out);
}

// Round 7
// 1262.297 us; speedup vs baseline: 1.4239x; 1.0814x over previous
//
#include <hip/hip_runtime.h>

#define BB 4
#define VV 50000
#define CC 128
#define KK 128
#define EE 400000
#define HH 128

#define CHUNK 512
#define NCHUNK 98        // ceil(VV/CHUNK)
#define PROJ_NCH 64      // v-chunks per batch for k_project (512-thread blocks)
#define TILES_PER_B 1563 // ceil(VV/32)  (unproject)
#define NT64 782         // ceil(VV/64)  (gradfeat / mlp)

typedef unsigned short u16;
typedef short bf16x8 __attribute__((ext_vector_type(8)));
typedef float f32x4 __attribute__((ext_vector_type(4)));

__device__ __forceinline__ u16 f2bf(float f) {
    union { float f; unsigned u; } x; x.f = f;
    unsigned r = x.u + 0x7FFFu + ((x.u >> 16) & 1u);
    return (u16)(r >> 16);
}
__device__ __forceinline__ float bf2f(u16 u) {
    union { unsigned u; float f; } x; x.u = ((unsigned)u) << 16;
    return x.f;
}
__device__ __forceinline__ unsigned pack2(float lo, float hi) {
    return ((unsigned)f2bf(hi) << 16) | (unsigned)f2bf(lo);
}
__device__ __forceinline__ float tanh_fast(float u) {
    float uc = fminf(fmaxf(u, -15.f), 15.f);
    float e = __expf(-2.f * uc);
    return (1.f - e) / (1.f + e);
}
__device__ __forceinline__ f32x4 fma4(float s, float4 v, f32x4 a) {
    a.x = fmaf(s, v.x, a.x);
    a.y = fmaf(s, v.y, a.y);
    a.z = fmaf(s, v.z, a.z);
    a.w = fmaf(s, v.w, a.w);
    return a;
}

// ---------------- utility ----------------
__global__ void k_zero_u32(unsigned int* __restrict__ p, int n) {
    int i = blockIdx.x * blockDim.x + threadIdx.x;
    if (i < n) p[i] = 0u;
}

// ---------------- edge bucketing (counting sort by row) ----------------
__global__ void k_hist(const int* __restrict__ rows, int* __restrict__ hist) {
    int idx = blockIdx.x * blockDim.x + threadIdx.x;
    if (idx >= BB * EE) return;
    int b = idx / EE;
    atomicAdd(&hist[b * VV + rows[idx]], 1);
}

__global__ void k_scan1(const int* __restrict__ hist, int* __restrict__ rs,
                        int* __restrict__ csum) {
    int t = threadIdx.x;
    if (t >= BB * NCHUNK) return;
    int b = t / NCHUNK, ch = t % NCHUNK;
    int base = ch * CHUNK;
    int sum = 0;
    for (int i = 0; i < CHUNK; ++i) {
        int v = base + i;
        if (v >= VV) break;
        int h = hist[b * VV + v];
        rs[b * VV + v] = sum;
        sum += h;
    }
    csum[b * 128 + ch] = sum;
}

__global__ void k_scan2(int* __restrict__ csum) {
    int b = threadIdx.x;
    if (b >= BB) return;
    int run = 0;
    for (int ch = 0; ch < NCHUNK; ++ch) {
        int t = csum[b * 128 + ch];
        csum[b * 128 + ch] = run;
        run += t;
    }
}

__global__ void k_scan3(int* __restrict__ rs, const int* __restrict__ csum,
                        int* __restrict__ cursor) {
    int idx = blockIdx.x * blockDim.x + threadIdx.x;
    if (idx >= BB * VV) return;
    int b = idx / VV, v = idx % VV;
    int r = rs[idx] + csum[b * 128 + v / CHUNK];
    rs[idx] = r;
    cursor[idx] = r;
}

__global__ void k_bucket(const int* __restrict__ rows, int* __restrict__ cursor,
                         int* __restrict__ edge_idx) {
    int idx = blockIdx.x * blockDim.x + threadIdx.x;
    if (idx >= BB * EE) return;
    int b = idx / EE, e = idx % EE;
    int r = rows[idx];
    int p = atomicAdd(&cursor[b * VV + r], 1);
    edge_idx[(size_t)b * EE + p] = e;
}

// ---------------- weight packing into MFMA B-fragment order ----------------
// B-frag layout (16x16x32): lane holds B[k = s*32 + (lane>>4)*8 + j][n = t*16 + (lane&15)]
// packed index: ((t*S + s)*64 + lane)*8 + j
__global__ void k_pack_rot(const float* __restrict__ Are, const float* __restrict__ Aim,
                           u16* __restrict__ Wre_p, u16* __restrict__ Wim_p) {
    int f = blockIdx.x * blockDim.x + threadIdx.x;  // 8t*8s*64 = 4096
    if (f >= 4096) return;
    int lane = f & 63;
    int s = (f >> 6) & 7;
    int t = f >> 9;
    int n = t * 16 + (lane & 15);
#pragma unroll
    for (int j = 0; j < 8; ++j) {
        int k = s * 32 + ((lane >> 4) << 3) + j;
        float re, im;
        if (k < 128) { re = Are[k * CC + n];           im = Aim[k * CC + n]; }
        else         { re = -Aim[(k - 128) * CC + n];  im = Are[(k - 128) * CC + n]; }
        Wre_p[(size_t)f * 8 + j] = f2bf(re);
        Wim_p[(size_t)f * 8 + j] = f2bf(im);
    }
}

__global__ void k_pack_w0(const float* __restrict__ W0, u16* __restrict__ W0p) {
    int f = blockIdx.x * blockDim.x + threadIdx.x;  // 8t*12s*64 = 6144
    if (f >= 6144) return;
    int lane = f & 63;
    int rem = f % 768;
    int s = rem >> 6;
    int t = f / 768;
    int n = t * 16 + (lane & 15);
#pragma unroll
    for (int j = 0; j < 8; ++j) {
        int k = s * 32 + ((lane >> 4) << 3) + j;
        W0p[(size_t)f * 8 + j] = f2bf(W0[(size_t)k * HH + n]);
    }
}

__global__ void k_pack_w1(const float* __restrict__ W1, u16* __restrict__ W1p) {
    int f = blockIdx.x * blockDim.x + threadIdx.x;  // 8t*4s*64 = 2048
    if (f >= 2048) return;
    int lane = f & 63;
    int s = (f >> 6) & 3;
    int t = f >> 8;
    int n = t * 16 + (lane & 15);
#pragma unroll
    for (int j = 0; j < 8; ++j) {
        int k = s * 32 + ((lane >> 4) << 3) + j;
        W1p[(size_t)f * 8 + j] = f2bf(W1[(size_t)k * CC + n]);
    }
}

// ---------------- stage A: spectral projection (fp32 vector, de-spilled) ----
__global__ __launch_bounds__(512) void k_project(
        const float* __restrict__ x_in, const float* __restrict__ mass,
        const float* __restrict__ evecs, float* __restrict__ spec) {
    __shared__ float evs[16][128];
    __shared__ float xs[16][128];
    int b  = blockIdx.x >> 6;
    int ch = blockIdx.x & 63;
    const int rowsPer = (VV + PROJ_NCH - 1) / PROJ_NCH;  // 782
    int vbase = ch * rowsPer;
    int vend  = min(vbase + rowsPer, VV);
    int t = threadIdx.x;
    int tk = t >> 5, tc = t & 31;
    int lrow = tk;
    int lc4  = tc * 4;

    f32x4 a0 = {0,0,0,0}, a1 = {0,0,0,0}, a2 = {0,0,0,0}, a3 = {0,0,0,0};
    f32x4 a4 = {0,0,0,0}, a5 = {0,0,0,0}, a6 = {0,0,0,0}, a7 = {0,0,0,0};

    float4 xr = make_float4(0.f, 0.f, 0.f, 0.f);
    float4 er = make_float4(0.f, 0.f, 0.f, 0.f);
    float  mr = 0.f;
    {
        int v = vbase + lrow;
        if (v < vend) {
            xr = *(const float4*)&x_in[((size_t)b * VV + v) * CC + lc4];
            er = *(const float4*)&evecs[((size_t)b * VV + v) * KK + lc4];
            mr = mass[b * VV + v];
        }
    }

    for (int v0 = vbase; v0 < vend; v0 += 16) {
        __syncthreads();
        *(float4*)&xs[lrow][lc4]  = make_float4(xr.x * mr, xr.y * mr, xr.z * mr, xr.w * mr);
        *(float4*)&evs[lrow][lc4] = er;
        __syncthreads();
        if (v0 + 16 < vend) {
            int v = v0 + 16 + lrow;
            if (v < vend) {
                xr = *(const float4*)&x_in[((size_t)b * VV + v) * CC + lc4];
                er = *(const float4*)&evecs[((size_t)b * VV + v) * KK + lc4];
                mr = mass[b * VV + v];
            } else {
                xr = make_float4(0.f, 0.f, 0.f, 0.f);
                er = make_float4(0.f, 0.f, 0.f, 0.f);
                mr = 0.f;
            }
        }
#pragma unroll
        for (int vv = 0; vv < 16; ++vv) {
            float4 xv = *(const float4*)&xs[vv][tc * 4];
            float4 ea = *(const float4*)&evs[vv][tk * 8];
            float4 eb = *(const float4*)&evs[vv][tk * 8 + 4];
            a0 = fma4(ea.x, xv, a0);
            a1 = fma4(ea.y, xv, a1);
            a2 = fma4(ea.z, xv, a2);
            a3 = fma4(ea.w, xv, a3);
            a4 = fma4(eb.x, xv, a4);
            a5 = fma4(eb.y, xv, a5);
            a6 = fma4(eb.z, xv, a6);
            a7 = fma4(eb.w, xv, a7);
        }
    }

    {
        size_t base = ((size_t)b * KK + tk * 8) * CC + tc * 4;
        float* p0 = &spec[base];
        atomicAdd(p0 + 0, a0.x); atomicAdd(p0 + 1, a0.y); atomicAdd(p0 + 2, a0.z); atomicAdd(p0 + 3, a0.w);
        float* p1 = p0 + CC;
        atomicAdd(p1 + 0, a1.x); atomicAdd(p1 + 1, a1.y); atomicAdd(p1 + 2, a1.z); atomicAdd(p1 + 3, a1.w);
        float* p2 = p0 + 2 * CC;
        atomicAdd(p2 + 0, a2.x); atomicAdd(p2 + 1, a2.y); atomicAdd(p2 + 2, a2.z); atomicAdd(p2 + 3, a2.w);
        float* p3 = p0 + 3 * CC;
        atomicAdd(p3 + 0, a3.x); atomicAdd(p3 + 1, a3.y); atomicAdd(p3 + 2, a3.z); atomicAdd(p3 + 3, a3.w);
        float* p4 = p0 + 4 * CC;
        atomicAdd(p4 + 0, a4.x); atomicAdd(p4 + 1, a4.y); atomicAdd(p4 + 2, a4.z); atomicAdd(p4 + 3, a4.w);
        float* p5 = p0 + 5 * CC;
        atomicAdd(p5 + 0, a5.x); atomicAdd(p5 + 1, a5.y); atomicAdd(p5 + 2, a5.z); atomicAdd(p5 + 3, a5.w);
        float* p6 = p0 + 6 * CC;
        atomicAdd(p6 + 0, a6.x); atomicAdd(p6 + 1, a6.y); atomicAdd(p6 + 2, a6.z); atomicAdd(p6 + 3, a6.w);
        float* p7 = p0 + 7 * CC;
        atomicAdd(p7 + 0, a7.x); atomicAdd(p7 + 1, a7.y); atomicAdd(p7 + 2, a7.z); atomicAdd(p7 + 3, a7.w);
    }
}

// ---------------- stage B: spectral decay ----------------
__global__ void k_decay(const float* __restrict__ spec, const float* __restrict__ evals,
                        const float* __restrict__ dt, float* __restrict__ spec_d) {
    int idx = blockIdx.x * blockDim.x + threadIdx.x;
    if (idx >= BB * KK * CC) return;
    int c = idx & 127;
    int k = (idx >> 7) & 127;
    int b = idx >> 14;
    float t = fmaxf(dt[c], 1e-8f);
    spec_d[idx] = spec[idx] * expf(-evals[b * KK + k] * t);
}

// ---------------- stage C: unproject (fp32 compute, bf16 out) ----------------
__global__ __launch_bounds__(256) void k_unproject(
        const float* __restrict__ evecs, const float* __restrict__ spec_d,
        u16* __restrict__ xd) {
    __shared__ float ss[128][128];
    __shared__ float evs[32][128];
    int b = blockIdx.x / TILES_PER_B;
    int vbase = (blockIdx.x % TILES_PER_B) * 32;
    int t = threadIdx.x;

#pragma unroll
    for (int l = 0; l < 16; ++l) {
        int idx4 = l * 256 + t;
        int row = idx4 >> 5;
        int c4 = (idx4 & 31) * 4;
        *(float4*)&ss[row][c4] = *(const float4*)&spec_d[((size_t)b * KK + row) * CC + c4];
    }
#pragma unroll
    for (int l = 0; l < 4; ++l) {
        int idx4 = l * 256 + t;
        int row = idx4 >> 5;
        int c4 = (idx4 & 31) * 4;
        int v = vbase + row;
        float4 e4 = make_float4(0.f, 0.f, 0.f, 0.f);
        if (v < VV) e4 = *(const float4*)&evecs[((size_t)b * VV + v) * KK + c4];
        *(float4*)&evs[row][c4] = e4;
    }
    __syncthreads();

    int cg = t & 31, vg = t >> 5;
    int c4 = cg * 4;
    float acc[4][4];
#pragma unroll
    for (int i = 0; i < 4; ++i)
#pragma unroll
        for (int q = 0; q < 4; ++q) acc[i][q] = 0.f;

#pragma unroll 8
    for (int k = 0; k < 128; ++k) {
        float4 s = *(float4*)&ss[k][c4];
#pragma unroll
        for (int i = 0; i < 4; ++i) {
            float ev = evs[vg * 4 + i][k];
            acc[i][0] = fmaf(ev, s.x, acc[i][0]);
            acc[i][1] = fmaf(ev, s.y, acc[i][1]);
            acc[i][2] = fmaf(ev, s.z, acc[i][2]);
            acc[i][3] = fmaf(ev, s.w, acc[i][3]);
        }
    }
#pragma unroll
    for (int i = 0; i < 4; ++i) {
        int v = vbase + vg * 4 + i;
        if (v < VV) {
            uint2 o;
            o.x = pack2(acc[i][0], acc[i][1]);
            o.y = pack2(acc[i][2], acc[i][3]);
            *(uint2*)&xd[(((size_t)b * VV + v) << 7) + c4] = o;
        }
    }
}

// ---------------- stage D: row-gathered SpMM (bf16 xd -> bf16 gx,gy) -------
// x4 unroll: 4 independent edge->col->gather chains in flight per wave
// (MLP fix for the dependent-chain stall; keeps round-4 edge_idx layout).
__global__ __launch_bounds__(256) void k_rowgather(
        const int* __restrict__ cols, const float* __restrict__ vxv,
        const float* __restrict__ vyv, const int* __restrict__ edge_idx,
        const int* __restrict__ rs, const int* __restrict__ cursor,
        const u16* __restrict__ xd, u16* __restrict__ gx, u16* __restrict__ gy) {
    int w = blockIdx.x * 4 + (threadIdx.x >> 6);
    int lane = threadIdx.x & 63;
    int b = w / VV;
    int beg = rs[w], end = cursor[w];
    float ax0 = 0.f, ax1 = 0.f, ay0 = 0.f, ay1 = 0.f;
    size_t ebase = (size_t)b * EE;
    const int* eb = edge_idx + ebase;
    const int* cb = cols + ebase;
    const float* fxb = vxv + ebase;
    const float* fyb = vyv + ebase;
    const u16* xdb = xd + (((size_t)b * VV) << 7) + lane * 2;
    int i = beg;
    for (; i + 4 <= end; i += 4) {
        int e0 = eb[i], e1 = eb[i + 1], e2 = eb[i + 2], e3 = eb[i + 3];
        int c0 = cb[e0], c1 = cb[e1], c2 = cb[e2], c3 = cb[e3];
        float fx0 = fxb[e0], fx1 = fxb[e1], fx2 = fxb[e2], fx3 = fxb[e3];
        float fy0 = fyb[e0], fy1 = fyb[e1], fy2 = fyb[e2], fy3 = fyb[e3];
        unsigned u0 = *(const unsigned*)&xdb[(size_t)c0 << 7];
        unsigned u1 = *(const unsigned*)&xdb[(size_t)c1 << 7];
        unsigned u2 = *(const unsigned*)&xdb[(size_t)c2 << 7];
        unsigned u3 = *(const unsigned*)&xdb[(size_t)c3 << 7];
        float x0, x1;
        x0 = bf2f((u16)(u0 & 0xFFFFu)); x1 = bf2f((u16)(u0 >> 16));
        ax0 = fmaf(fx0, x0, ax0); ax1 = fmaf(fx0, x1, ax1);
        ay0 = fmaf(fy0, x0, ay0); ay1 = fmaf(fy0, x1, ay1);
        x0 = bf2f((u16)(u1 & 0xFFFFu)); x1 = bf2f((u16)(u1 >> 16));
        ax0 = fmaf(fx1, x0, ax0); ax1 = fmaf(fx1, x1, ax1);
        ay0 = fmaf(fy1, x0, ay0); ay1 = fmaf(fy1, x1, ay1);
        x0 = bf2f((u16)(u2 & 0xFFFFu)); x1 = bf2f((u16)(u2 >> 16));
        ax0 = fmaf(fx2, x0, ax0); ax1 = fmaf(fx2, x1, ax1);
        ay0 = fmaf(fy2, x0, ay0); ay1 = fmaf(fy2, x1, ay1);
        x0 = bf2f((u16)(u3 & 0xFFFFu)); x1 = bf2f((u16)(u3 >> 16));
        ax0 = fmaf(fx3, x0, ax0); ax1 = fmaf(fx3, x1, ax1);
        ay0 = fmaf(fy3, x0, ay0); ay1 = fmaf(fy3, x1, ay1);
    }
    for (; i < end; ++i) {
        int e0 = eb[i];
        int c0 = cb[e0];
        float fx0 = fxb[e0], fy0 = fyb[e0];
        unsigned u0 = *(const unsigned*)&xdb[(size_t)c0 << 7];
        float x0 = bf2f((u16)(u0 & 0xFFFFu)), x1 = bf2f((u16)(u0 >> 16));
        ax0 = fmaf(fx0, x0, ax0); ax1 = fmaf(fx0, x1, ax1);
        ay0 = fmaf(fy0, x0, ay0); ay1 = fmaf(fy0, x1, ay1);
    }
    size_t ro = ((size_t)w << 7) + lane * 2;
    *(unsigned*)&gx[ro] = pack2(ax0, ax1);
    *(unsigned*)&gy[ro] = pack2(ay0, ay1);
}

// ---------------- stage E: spatial gradient features (MFMA bf16) -----------
__global__ __launch_bounds__(256) void k_gradfeat(
        const u16* __restrict__ gx, const u16* __restrict__ gy,
        const u16* __restrict__ Wre_p, const u16* __restrict__ Wim_p,
        u16* __restrict__ xgf) {
    __shared__ u16 Gs[64][264];     // [gx | gy] bf16, padded stride
    __shared__ u16 Bre[8][64][8];
    __shared__ u16 Bim[8][64][8];
    int b = blockIdx.x / NT64;
    int vbase = (blockIdx.x % NT64) * 64;
    int t = threadIdx.x;
    int lane = t & 63, w = t >> 6;
    {
        int row = t >> 2, p = t & 3;
        int v = vbase + row;
        bool ok = v < VV;
        size_t ro = ((size_t)b * VV + (ok ? v : 0)) << 7;
        const uint4* gxr = (const uint4*)&gx[ro + p * 32];
        const uint4* gyr = (const uint4*)&gy[ro + p * 32];
        uint4 z = make_uint4(0u, 0u, 0u, 0u);
#pragma unroll
        for (int i = 0; i < 4; ++i) {
            uint4 a = ok ? gxr[i] : z;
            uint4 c = ok ? gyr[i] : z;
            *(uint4*)&Gs[row][p * 32 + i * 8] = a;
            *(uint4*)&Gs[row][128 + p * 32 + i * 8] = c;
        }
    }
    __syncthreads();
    int m = lane & 15, q = lane >> 4;
    bf16x8 afr[8];
#pragma unroll
    for (int s = 0; s < 8; ++s)
        afr[s] = *(const bf16x8*)&Gs[w * 16 + m][s * 32 + q * 8];

    for (int tt = 0; tt < 8; ++tt) {
        __syncthreads();
        {
            const uint4* sre = (const uint4*)&Wre_p[(size_t)tt * 4096];
            const uint4* sim = (const uint4*)&Wim_p[(size_t)tt * 4096];
            uint4* dre = (uint4*)&Bre[0][0][0];
            uint4* dim = (uint4*)&Bim[0][0][0];
            dre[t] = sre[t]; dre[t + 256] = sre[t + 256];
            dim[t] = sim[t]; dim[t + 256] = sim[t + 256];
        }
        __syncthreads();
        f32x4 are = {0.f, 0.f, 0.f, 0.f};
        f32x4 aim = {0.f, 0.f, 0.f, 0.f};
#pragma unroll
        for (int s = 0; s < 8; ++s) {
            bf16x8 br = *(const bf16x8*)&Bre[s][lane][0];
            bf16x8 bi = *(const bf16x8*)&Bim[s][lane][0];
            are = __builtin_amdgcn_mfma_f32_16x16x32_bf16(afr[s], br, are, 0, 0, 0);
            aim = __builtin_amdgcn_mfma_f32_16x16x32_bf16(afr[s], bi, aim, 0, 0, 0);
        }
#pragma unroll
        for (int r = 0; r < 4; ++r) {
            int row = w * 16 + q * 4 + r;
            int v = vbase + row;
            if (v < VV) {
                float gxv = bf2f(Gs[row][tt * 16 + m]);
                float gyv = bf2f(Gs[row][128 + tt * 16 + m]);
                float u = gxv * are[r] + gyv * aim[r];
                xgf[(((size_t)b * VV + v) << 7) + tt * 16 + m] = f2bf(tanh_fast(u));
            }
        }
    }
}

// ---------------- stage F: fused MLP + residual (MFMA bf16) ----------------
__global__ __launch_bounds__(256) void k_mlp(
        const float* __restrict__ x_in, const u16* __restrict__ xd,
        const u16* __restrict__ xgf,
        const u16* __restrict__ W0p, const float* __restrict__ b0,
        const u16* __restrict__ W1p, const float* __restrict__ b1,
        float* __restrict__ out) {
    __shared__ u16 Fs[64][392];     // [x_in | xd | xgf] bf16, padded stride
    __shared__ u16 Hs[64][136];     // hidden, padded stride
    __shared__ u16 Bs[12][64][8];
    int b = blockIdx.x / NT64;
    int vbase = (blockIdx.x % NT64) * 64;
    int t = threadIdx.x;
    int lane = t & 63, w = t >> 6;
    {
        int row = t >> 2, p = t & 3;
        int v = vbase + row;
        bool ok = v < VV;
        size_t ro = ((size_t)b * VV + (ok ? v : 0)) << 7;
        const float4* xir = (const float4*)&x_in[ro + p * 32];
#pragma unroll
        for (int i = 0; i < 8; ++i) {
            float4 f = ok ? xir[i] : make_float4(0.f, 0.f, 0.f, 0.f);
            uint2 u;
            u.x = pack2(f.x, f.y);
            u.y = pack2(f.z, f.w);
            *(uint2*)&Fs[row][p * 32 + i * 4] = u;
        }
        const uint4* xdr = (const uint4*)&xd[ro + p * 32];
        const uint4* xgr = (const uint4*)&xgf[ro + p * 32];
        uint4 z = make_uint4(0u, 0u, 0u, 0u);
#pragma unroll
        for (int i = 0; i < 4; ++i) {
            uint4 a = ok ? xdr[i] : z;
            uint4 c = ok ? xgr[i] : z;
            *(uint4*)&Fs[row][128 + p * 32 + i * 8] = a;
            *(uint4*)&Fs[row][256 + p * 32 + i * 8] = c;
        }
    }
    __syncthreads();
    int m = lane & 15, q = lane >> 4;
    bf16x8 af[12];
#pragma unroll
    for (int s = 0; s < 12; ++s)
        af[s] = *(const bf16x8*)&Fs[w * 16 + m][s * 32 + q * 8];

    // GEMM1: feat @ W0 + b0 -> relu -> Hs
    for (int tt = 0; tt < 8; ++tt) {
        __syncthreads();
        {
            const uint4* src = (const uint4*)&W0p[(size_t)tt * 6144];
            uint4* d = (uint4*)&Bs[0][0][0];
            d[t] = src[t];
            d[t + 256] = src[t + 256];
            d[t + 512] = src[t + 512];
        }
        __syncthreads();
        f32x4 acc = {0.f, 0.f, 0.f, 0.f};
#pragma unroll
        for (int s = 0; s < 12; ++s) {
            bf16x8 bb = *(const bf16x8*)&Bs[s][lane][0];
            acc = __builtin_amdgcn_mfma_f32_16x16x32_bf16(af[s], bb, acc, 0, 0, 0);
        }
        float bias = b0[tt * 16 + m];
#pragma unroll
        for (int r = 0; r < 4; ++r) {
            Hs[w * 16 + q * 4 + r][tt * 16 + m] = f2bf(fmaxf(acc[r] + bias, 0.f));
        }
    }

    // GEMM2: h @ W1 + b1 + x_in -> out (A-frags from own wave's Hs rows)
    bf16x8 ah[4];
    for (int tt = 0; tt < 8; ++tt) {
        __syncthreads();
        {
            const uint4* src = (const uint4*)&W1p[(size_t)tt * 2048];
            uint4* d = (uint4*)&Bs[0][0][0];
            d[t] = src[t];
        }
        if (tt == 0) {
#pragma unroll
            for (int s = 0; s < 4; ++s)
                ah[s] = *(const bf16x8*)&Hs[w * 16 + m][s * 32 + q * 8];
        }
        __syncthreads();
        f32x4 acc = {0.f, 0.f, 0.f, 0.f};
#pragma unroll
        for (int s = 0; s < 4; ++s) {
            bf16x8 bb = *(const bf16x8*)&Bs[s][lane][0];
            acc = __builtin_amdgcn_mfma_f32_16x16x32_bf16(ah[s], bb, acc, 0, 0, 0);
        }
        float bias = b1[tt * 16 + m];
#pragma unroll
        for (int r = 0; r < 4; ++r) {
            int row = w * 16 + q * 4 + r;
            int v = vbase + row;
            if (v < VV) {
                size_t off = (((size_t)b * VV + v) << 7) + tt * 16 + m;
                out[off] = acc[r] + bias + x_in[off];
            }
        }
    }
}

extern "C" void kernel_launch(void* const* d_in, const int* in_sizes, int n_in,
                              void* d_out, int out_size, void* d_ws, size_t ws_size,
                              hipStream_t stream) {
    (void)in_sizes; (void)n_in; (void)out_size; (void)ws_size;
    const float* x_in  = (const float*)d_in[0];
    const float* mass  = (const float*)d_in[1];
    const float* evals = (const float*)d_in[3];
    const float* evecs = (const float*)d_in[4];
    const int* grad_rows = (const int*)d_in[5];
    const int* grad_cols = (const int*)d_in[6];
    const float* gX = (const float*)d_in[7];
    const float* gY = (const float*)d_in[8];
    const float* dt  = (const float*)d_in[9];
    const float* Are = (const float*)d_in[10];
    const float* Aim = (const float*)d_in[11];
    const float* W0 = (const float*)d_in[12];
    const float* b0 = (const float*)d_in[13];
    const float* W1 = (const float*)d_in[14];
    const float* b1 = (const float*)d_in[15];
    float* out = (float*)d_out;

    char* w = (char*)d_ws;
    u16* xd  = (u16*)w; w += (size_t)BB * VV * CC * 2;
    u16* gx  = (u16*)w; w += (size_t)BB * VV * CC * 2;
    u16* gy  = (u16*)w; w += (size_t)BB * VV * CC * 2;
    u16* xgf = (u16*)w; w += (size_t)BB * VV * CC * 2;
    float* spec   = (float*)w; w += (size_t)BB * KK * CC * 4;
    float* spec_d = (float*)w; w += (size_t)BB * KK * CC * 4;
    int* hist   = (int*)w; w += (size_t)BB * VV * 4;
    int* rs     = (int*)w; w += (size_t)BB * VV * 4;
    int* cursor = (int*)w; w += (size_t)BB * VV * 4;
    int* csum   = (int*)w; w += (size_t)BB * 128 * 4;
    int* edge_idx = (int*)w; w += (size_t)BB * EE * 4;
    u16* Wre_p = (u16*)w; w += (size_t)4096 * 8 * 2;
    u16* Wim_p = (u16*)w; w += (size_t)4096 * 8 * 2;
    u16* W0p   = (u16*)w; w += (size_t)6144 * 8 * 2;
    u16* W1p   = (u16*)w; w += (size_t)2048 * 8 * 2;

    hipLaunchKernelGGL(k_zero_u32, dim3((BB * VV + 255) / 256), dim3(256), 0, stream,
                       (unsigned int*)hist, BB * VV);
    hipLaunchKernelGGL(k_zero_u32, dim3((BB * KK * CC + 255) / 256), dim3(256), 0, stream,
                       (unsigned int*)spec, BB * KK * CC);
    hipLaunchKernelGGL(k_hist, dim3((BB * EE + 255) / 256), dim3(256), 0, stream,
                       grad_rows, hist);
    hipLaunchKernelGGL(k_scan1, dim3(1), dim3(512), 0, stream, hist, rs, csum);
    hipLaunchKernelGGL(k_scan2, dim3(1), dim3(64), 0, stream, csum);
    hipLaunchKernelGGL(k_scan3, dim3((BB * VV + 255) / 256), dim3(256), 0, stream,
                       rs, csum, cursor);
    hipLaunchKernelGGL(k_bucket, dim3((BB * EE + 255) / 256), dim3(256), 0, stream,
                       grad_rows, cursor, edge_idx);
    hipLaunchKernelGGL(k_pack_rot, dim3(16), dim3(256), 0, stream, Are, Aim, Wre_p, Wim_p);
    hipLaunchKernelGGL(k_pack_w0, dim3(24), dim3(256), 0, stream, W0, W0p);
    hipLaunchKernelGGL(k_pack_w1, dim3(8), dim3(256), 0, stream, W1, W1p);
    hipLaunchKernelGGL(k_project, dim3(BB * PROJ_NCH), dim3(512), 0, stream,
                       x_in, mass, evecs, spec);
    hipLaunchKernelGGL(k_decay, dim3((BB * KK * CC + 255) / 256), dim3(256), 0, stream,
                       spec, evals, dt, spec_d);
    hipLaunchKernelGGL(k_unproject, dim3(BB * TILES_PER_B), dim3(256), 0, stream,
                       evecs, spec_d, xd);
    hipLaunchKernelGGL(k_rowgather, dim3(BB * VV / 4), dim3(256), 0, stream,
                       grad_cols, gX, gY, edge_idx, rs, cursor, xd, gx, gy);
    hipLaunchKernelGGL(k_gradfeat, dim3(BB * NT64), dim3(256), 0, stream,
                       gx, gy, Wre_p, Wim_p, xgf);
    hipLaunchKernelGGL(k_mlp, dim3(BB * NT64), dim3(256), 0, stream,
                       x_in, xd, xgf, W0p, b0, W1p, b1, out);
}

// Round 8
// 1013.860 us; speedup vs baseline: 1.7728x; 1.2450x over previous
//
#include <hip/hip_runtime.h>

#define BB 4
#define VV 50000
#define CC 128
#define KK 128
#define EE 400000
#define HH 128

#define CHUNK 512
#define NCHUNK 98        // ceil(VV/CHUNK)
#define PROJ_NCH 64      // v-chunks per batch for k_project (512-thread blocks)
#define TILES_PER_B 1563 // ceil(VV/32)  (unproject)
#define NT64 782         // ceil(VV/64)  (gradfeat / mlp)

typedef unsigned short u16;
typedef short bf16x8 __attribute__((ext_vector_type(8)));
typedef float f32x4 __attribute__((ext_vector_type(4)));

__device__ __forceinline__ u16 f2bf(float f) {
    union { float f; unsigned u; } x; x.f = f;
    unsigned r = x.u + 0x7FFFu + ((x.u >> 16) & 1u);
    return (u16)(r >> 16);
}
__device__ __forceinline__ float bf2f(u16 u) {
    union { unsigned u; float f; } x; x.u = ((unsigned)u) << 16;
    return x.f;
}
__device__ __forceinline__ unsigned pack2(float lo, float hi) {
    return ((unsigned)f2bf(hi) << 16) | (unsigned)f2bf(lo);
}
__device__ __forceinline__ float tanh_fast(float u) {
    float uc = fminf(fmaxf(u, -15.f), 15.f);
    float e = __expf(-2.f * uc);
    return (1.f - e) / (1.f + e);
}
__device__ __forceinline__ f32x4 fma4(float s, float4 v, f32x4 a) {
    a.x = fmaf(s, v.x, a.x);
    a.y = fmaf(s, v.y, a.y);
    a.z = fmaf(s, v.z, a.z);
    a.w = fmaf(s, v.w, a.w);
    return a;
}

// ---------------- utility ----------------
__global__ void k_zero_u32(unsigned int* __restrict__ p, int n) {
    int i = blockIdx.x * blockDim.x + threadIdx.x;
    if (i < n) p[i] = 0u;
}

// ---------------- edge bucketing (counting sort by row) ----------------
__global__ void k_hist(const int* __restrict__ rows, int* __restrict__ hist) {
    int idx = blockIdx.x * blockDim.x + threadIdx.x;
    if (idx >= BB * EE) return;
    int b = idx / EE;
    atomicAdd(&hist[b * VV + rows[idx]], 1);
}

// parallel per-chunk exclusive scan: one block per (batch, chunk), LDS
// Hillis-Steele over 512 entries. (was: 1 block, serial 512-walk/thread,
// 252 us at 0.08% occupancy)
__global__ __launch_bounds__(512) void k_scan1(const int* __restrict__ hist,
                                               int* __restrict__ rs,
                                               int* __restrict__ csum) {
    __shared__ int sh[512];
    int bc = blockIdx.x;          // 0..BB*NCHUNK-1
    int b = bc / NCHUNK, ch = bc % NCHUNK;
    int base = ch * CHUNK;
    int t = threadIdx.x;
    int v = base + t;
    int h = (v < VV) ? hist[b * VV + v] : 0;
    sh[t] = h;
    __syncthreads();
#pragma unroll
    for (int off = 1; off < 512; off <<= 1) {
        int val = (t >= off) ? sh[t - off] : 0;
        __syncthreads();
        if (t >= off) sh[t] += val;
        __syncthreads();
    }
    int incl = sh[t];
    if (v < VV) rs[b * VV + v] = incl - h;
    if (t == 511) csum[b * 128 + ch] = incl;
}

// chunk-total scan: parallel LDS load, 4-thread serial scan in LDS,
// parallel write-back. (was: serial 98-step global walk)
__global__ __launch_bounds__(512) void k_scan2(int* __restrict__ csum) {
    __shared__ int sh[BB][NCHUNK];
    int t = threadIdx.x;
    int b = t / NCHUNK, ch = t % NCHUNK;
    if (t < BB * NCHUNK) sh[b][ch] = csum[b * 128 + ch];
    __syncthreads();
    if (t < BB) {
        int run = 0;
#pragma unroll 2
        for (int c = 0; c < NCHUNK; ++c) {
            int v = sh[t][c];
            sh[t][c] = run;
            run += v;
        }
    }
    __syncthreads();
    if (t < BB * NCHUNK) csum[b * 128 + ch] = sh[b][ch];
}

__global__ void k_scan3(int* __restrict__ rs, const int* __restrict__ csum,
                        int* __restrict__ cursor) {
    int idx = blockIdx.x * blockDim.x + threadIdx.x;
    if (idx >= BB * VV) return;
    int b = idx / VV, v = idx % VV;
    int r = rs[idx] + csum[b * 128 + v / CHUNK];
    rs[idx] = r;
    cursor[idx] = r;
}

__global__ void k_bucket(const int* __restrict__ rows, int* __restrict__ cursor,
                         int* __restrict__ edge_idx) {
    int idx = blockIdx.x * blockDim.x + threadIdx.x;
    if (idx >= BB * EE) return;
    int b = idx / EE, e = idx % EE;
    int r = rows[idx];
    int p = atomicAdd(&cursor[b * VV + r], 1);
    edge_idx[(size_t)b * EE + p] = e;
}

// ---------------- weight packing into MFMA B-fragment order ----------------
// B-frag layout (16x16x32): lane holds B[k = s*32 + (lane>>4)*8 + j][n = t*16 + (lane&15)]
// packed index: ((t*S + s)*64 + lane)*8 + j
__global__ void k_pack_rot(const float* __restrict__ Are, const float* __restrict__ Aim,
                           u16* __restrict__ Wre_p, u16* __restrict__ Wim_p) {
    int f = blockIdx.x * blockDim.x + threadIdx.x;  // 8t*8s*64 = 4096
    if (f >= 4096) return;
    int lane = f & 63;
    int s = (f >> 6) & 7;
    int t = f >> 9;
    int n = t * 16 + (lane & 15);
#pragma unroll
    for (int j = 0; j < 8; ++j) {
        int k = s * 32 + ((lane >> 4) << 3) + j;
        float re, im;
        if (k < 128) { re = Are[k * CC + n];           im = Aim[k * CC + n]; }
        else         { re = -Aim[(k - 128) * CC + n];  im = Are[(k - 128) * CC + n]; }
        Wre_p[(size_t)f * 8 + j] = f2bf(re);
        Wim_p[(size_t)f * 8 + j] = f2bf(im);
    }
}

__global__ void k_pack_w0(const float* __restrict__ W0, u16* __restrict__ W0p) {
    int f = blockIdx.x * blockDim.x + threadIdx.x;  // 8t*12s*64 = 6144
    if (f >= 6144) return;
    int lane = f & 63;
    int rem = f % 768;
    int s = rem >> 6;
    int t = f / 768;
    int n = t * 16 + (lane & 15);
#pragma unroll
    for (int j = 0; j < 8; ++j) {
        int k = s * 32 + ((lane >> 4) << 3) + j;
        W0p[(size_t)f * 8 + j] = f2bf(W0[(size_t)k * HH + n]);
    }
}

__global__ void k_pack_w1(const float* __restrict__ W1, u16* __restrict__ W1p) {
    int f = blockIdx.x * blockDim.x + threadIdx.x;  // 8t*4s*64 = 2048
    if (f >= 2048) return;
    int lane = f & 63;
    int s = (f >> 6) & 3;
    int t = f >> 8;
    int n = t * 16 + (lane & 15);
#pragma unroll
    for (int j = 0; j < 8; ++j) {
        int k = s * 32 + ((lane >> 4) << 3) + j;
        W1p[(size_t)f * 8 + j] = f2bf(W1[(size_t)k * CC + n]);
    }
}

// ---------------- stage A: spectral projection (fp32 vector, de-spilled) ----
__global__ __launch_bounds__(512) void k_project(
        const float* __restrict__ x_in, const float* __restrict__ mass,
        const float* __restrict__ evecs, float* __restrict__ spec) {
    __shared__ float evs[16][128];
    __shared__ float xs[16][128];
    int b  = blockIdx.x >> 6;
    int ch = blockIdx.x & 63;
    const int rowsPer = (VV + PROJ_NCH - 1) / PROJ_NCH;  // 782
    int vbase = ch * rowsPer;
    int vend  = min(vbase + rowsPer, VV);
    int t = threadIdx.x;
    int tk = t >> 5, tc = t & 31;
    int lrow = tk;
    int lc4  = tc * 4;

    f32x4 a0 = {0,0,0,0}, a1 = {0,0,0,0}, a2 = {0,0,0,0}, a3 = {0,0,0,0};
    f32x4 a4 = {0,0,0,0}, a5 = {0,0,0,0}, a6 = {0,0,0,0}, a7 = {0,0,0,0};

    float4 xr = make_float4(0.f, 0.f, 0.f, 0.f);
    float4 er = make_float4(0.f, 0.f, 0.f, 0.f);
    float  mr = 0.f;
    {
        int v = vbase + lrow;
        if (v < vend) {
            xr = *(const float4*)&x_in[((size_t)b * VV + v) * CC + lc4];
            er = *(const float4*)&evecs[((size_t)b * VV + v) * KK + lc4];
            mr = mass[b * VV + v];
        }
    }

    for (int v0 = vbase; v0 < vend; v0 += 16) {
        __syncthreads();
        *(float4*)&xs[lrow][lc4]  = make_float4(xr.x * mr, xr.y * mr, xr.z * mr, xr.w * mr);
        *(float4*)&evs[lrow][lc4] = er;
        __syncthreads();
        if (v0 + 16 < vend) {
            int v = v0 + 16 + lrow;
            if (v < vend) {
                xr = *(const float4*)&x_in[((size_t)b * VV + v) * CC + lc4];
                er = *(const float4*)&evecs[((size_t)b * VV + v) * KK + lc4];
                mr = mass[b * VV + v];
            } else {
                xr = make_float4(0.f, 0.f, 0.f, 0.f);
                er = make_float4(0.f, 0.f, 0.f, 0.f);
                mr = 0.f;
            }
        }
#pragma unroll
        for (int vv = 0; vv < 16; ++vv) {
            float4 xv = *(const float4*)&xs[vv][tc * 4];
            float4 ea = *(const float4*)&evs[vv][tk * 8];
            float4 eb = *(const float4*)&evs[vv][tk * 8 + 4];
            a0 = fma4(ea.x, xv, a0);
            a1 = fma4(ea.y, xv, a1);
            a2 = fma4(ea.z, xv, a2);
            a3 = fma4(ea.w, xv, a3);
            a4 = fma4(eb.x, xv, a4);
            a5 = fma4(eb.y, xv, a5);
            a6 = fma4(eb.z, xv, a6);
            a7 = fma4(eb.w, xv, a7);
        }
    }

    {
        size_t base = ((size_t)b * KK + tk * 8) * CC + tc * 4;
        float* p0 = &spec[base];
        atomicAdd(p0 + 0, a0.x); atomicAdd(p0 + 1, a0.y); atomicAdd(p0 + 2, a0.z); atomicAdd(p0 + 3, a0.w);
        float* p1 = p0 + CC;
        atomicAdd(p1 + 0, a1.x); atomicAdd(p1 + 1, a1.y); atomicAdd(p1 + 2, a1.z); atomicAdd(p1 + 3, a1.w);
        float* p2 = p0 + 2 * CC;
        atomicAdd(p2 + 0, a2.x); atomicAdd(p2 + 1, a2.y); atomicAdd(p2 + 2, a2.z); atomicAdd(p2 + 3, a2.w);
        float* p3 = p0 + 3 * CC;
        atomicAdd(p3 + 0, a3.x); atomicAdd(p3 + 1, a3.y); atomicAdd(p3 + 2, a3.z); atomicAdd(p3 + 3, a3.w);
        float* p4 = p0 + 4 * CC;
        atomicAdd(p4 + 0, a4.x); atomicAdd(p4 + 1, a4.y); atomicAdd(p4 + 2, a4.z); atomicAdd(p4 + 3, a4.w);
        float* p5 = p0 + 5 * CC;
        atomicAdd(p5 + 0, a5.x); atomicAdd(p5 + 1, a5.y); atomicAdd(p5 + 2, a5.z); atomicAdd(p5 + 3, a5.w);
        float* p6 = p0 + 6 * CC;
        atomicAdd(p6 + 0, a6.x); atomicAdd(p6 + 1, a6.y); atomicAdd(p6 + 2, a6.z); atomicAdd(p6 + 3, a6.w);
        float* p7 = p0 + 7 * CC;
        atomicAdd(p7 + 0, a7.x); atomicAdd(p7 + 1, a7.y); atomicAdd(p7 + 2, a7.z); atomicAdd(p7 + 3, a7.w);
    }
}

// ---------------- stage B: spectral decay ----------------
__global__ void k_decay(const float* __restrict__ spec, const float* __restrict__ evals,
                        const float* __restrict__ dt, float* __restrict__ spec_d) {
    int idx = blockIdx.x * blockDim.x + threadIdx.x;
    if (idx >= BB * KK * CC) return;
    int c = idx & 127;
    int k = (idx >> 7) & 127;
    int b = idx >> 14;
    float t = fmaxf(dt[c], 1e-8f);
    spec_d[idx] = spec[idx] * expf(-evals[b * KK + k] * t);
}

// ---------------- stage C: unproject (fp32 compute, bf16 out) ----------------
__global__ __launch_bounds__(256) void k_unproject(
        const float* __restrict__ evecs, const float* __restrict__ spec_d,
        u16* __restrict__ xd) {
    __shared__ float ss[128][128];
    __shared__ float evs[32][128];
    int b = blockIdx.x / TILES_PER_B;
    int vbase = (blockIdx.x % TILES_PER_B) * 32;
    int t = threadIdx.x;

#pragma unroll
    for (int l = 0; l < 16; ++l) {
        int idx4 = l * 256 + t;
        int row = idx4 >> 5;
        int c4 = (idx4 & 31) * 4;
        *(float4*)&ss[row][c4] = *(const float4*)&spec_d[((size_t)b * KK + row) * CC + c4];
    }
#pragma unroll
    for (int l = 0; l < 4; ++l) {
        int idx4 = l * 256 + t;
        int row = idx4 >> 5;
        int c4 = (idx4 & 31) * 4;
        int v = vbase + row;
        float4 e4 = make_float4(0.f, 0.f, 0.f, 0.f);
        if (v < VV) e4 = *(const float4*)&evecs[((size_t)b * VV + v) * KK + c4];
        *(float4*)&evs[row][c4] = e4;
    }
    __syncthreads();

    int cg = t & 31, vg = t >> 5;
    int c4 = cg * 4;
    float acc[4][4];
#pragma unroll
    for (int i = 0; i < 4; ++i)
#pragma unroll
        for (int q = 0; q < 4; ++q) acc[i][q] = 0.f;

#pragma unroll 8
    for (int k = 0; k < 128; ++k) {
        float4 s = *(float4*)&ss[k][c4];
#pragma unroll
        for (int i = 0; i < 4; ++i) {
            float ev = evs[vg * 4 + i][k];
            acc[i][0] = fmaf(ev, s.x, acc[i][0]);
            acc[i][1] = fmaf(ev, s.y, acc[i][1]);
            acc[i][2] = fmaf(ev, s.z, acc[i][2]);
            acc[i][3] = fmaf(ev, s.w, acc[i][3]);
        }
    }
#pragma unroll
    for (int i = 0; i < 4; ++i) {
        int v = vbase + vg * 4 + i;
        if (v < VV) {
            uint2 o;
            o.x = pack2(acc[i][0], acc[i][1]);
            o.y = pack2(acc[i][2], acc[i][3]);
            *(uint2*)&xd[(((size_t)b * VV + v) << 7) + c4] = o;
        }
    }
}

// ---------------- stage D: row-gathered SpMM (bf16 xd -> bf16 gx,gy) -------
// x4 unroll: 4 independent edge->col->gather chains in flight per wave
__global__ __launch_bounds__(256) void k_rowgather(
        const int* __restrict__ cols, const float* __restrict__ vxv,
        const float* __restrict__ vyv, const int* __restrict__ edge_idx,
        const int* __restrict__ rs, const int* __restrict__ cursor,
        const u16* __restrict__ xd, u16* __restrict__ gx, u16* __restrict__ gy) {
    int w = blockIdx.x * 4 + (threadIdx.x >> 6);
    int lane = threadIdx.x & 63;
    int b = w / VV;
    int beg = rs[w], end = cursor[w];
    float ax0 = 0.f, ax1 = 0.f, ay0 = 0.f, ay1 = 0.f;
    size_t ebase = (size_t)b * EE;
    const int* eb = edge_idx + ebase;
    const int* cb = cols + ebase;
    const float* fxb = vxv + ebase;
    const float* fyb = vyv + ebase;
    const u16* xdb = xd + (((size_t)b * VV) << 7) + lane * 2;
    int i = beg;
    for (; i + 4 <= end; i += 4) {
        int e0 = eb[i], e1 = eb[i + 1], e2 = eb[i + 2], e3 = eb[i + 3];
        int c0 = cb[e0], c1 = cb[e1], c2 = cb[e2], c3 = cb[e3];
        float fx0 = fxb[e0], fx1 = fxb[e1], fx2 = fxb[e2], fx3 = fxb[e3];
        float fy0 = fyb[e0], fy1 = fyb[e1], fy2 = fyb[e2], fy3 = fyb[e3];
        unsigned u0 = *(const unsigned*)&xdb[(size_t)c0 << 7];
        unsigned u1 = *(const unsigned*)&xdb[(size_t)c1 << 7];
        unsigned u2 = *(const unsigned*)&xdb[(size_t)c2 << 7];
        unsigned u3 = *(const unsigned*)&xdb[(size_t)c3 << 7];
        float x0, x1;
        x0 = bf2f((u16)(u0 & 0xFFFFu)); x1 = bf2f((u16)(u0 >> 16));
        ax0 = fmaf(fx0, x0, ax0); ax1 = fmaf(fx0, x1, ax1);
        ay0 = fmaf(fy0, x0, ay0); ay1 = fmaf(fy0, x1, ay1);
        x0 = bf2f((u16)(u1 & 0xFFFFu)); x1 = bf2f((u16)(u1 >> 16));
        ax0 = fmaf(fx1, x0, ax0); ax1 = fmaf(fx1, x1, ax1);
        ay0 = fmaf(fy1, x0, ay0); ay1 = fmaf(fy1, x1, ay1);
        x0 = bf2f((u16)(u2 & 0xFFFFu)); x1 = bf2f((u16)(u2 >> 16));
        ax0 = fmaf(fx2, x0, ax0); ax1 = fmaf(fx2, x1, ax1);
        ay0 = fmaf(fy2, x0, ay0); ay1 = fmaf(fy2, x1, ay1);
        x0 = bf2f((u16)(u3 & 0xFFFFu)); x1 = bf2f((u16)(u3 >> 16));
        ax0 = fmaf(fx3, x0, ax0); ax1 = fmaf(fx3, x1, ax1);
        ay0 = fmaf(fy3, x0, ay0); ay1 = fmaf(fy3, x1, ay1);
    }
    for (; i < end; ++i) {
        int e0 = eb[i];
        int c0 = cb[e0];
        float fx0 = fxb[e0], fy0 = fyb[e0];
        unsigned u0 = *(const unsigned*)&xdb[(size_t)c0 << 7];
        float x0 = bf2f((u16)(u0 & 0xFFFFu)), x1 = bf2f((u16)(u0 >> 16));
        ax0 = fmaf(fx0, x0, ax0); ax1 = fmaf(fx0, x1, ax1);
        ay0 = fmaf(fy0, x0, ay0); ay1 = fmaf(fy0, x1, ay1);
    }
    size_t ro = ((size_t)w << 7) + lane * 2;
    *(unsigned*)&gx[ro] = pack2(ax0, ax1);
    *(unsigned*)&gy[ro] = pack2(ay0, ay1);
}

// ---------------- stage E: spatial gradient features (MFMA bf16) -----------
__global__ __launch_bounds__(256) void k_gradfeat(
        const u16* __restrict__ gx, const u16* __restrict__ gy,
        const u16* __restrict__ Wre_p, const u16* __restrict__ Wim_p,
        u16* __restrict__ xgf) {
    __shared__ u16 Gs[64][264];     // [gx | gy] bf16, padded stride
    __shared__ u16 Bre[8][64][8];
    __shared__ u16 Bim[8][64][8];
    int b = blockIdx.x / NT64;
    int vbase = (blockIdx.x % NT64) * 64;
    int t = threadIdx.x;
    int lane = t & 63, w = t >> 6;
    {
        int row = t >> 2, p = t & 3;
        int v = vbase + row;
        bool ok = v < VV;
        size_t ro = ((size_t)b * VV + (ok ? v : 0)) << 7;
        const uint4* gxr = (const uint4*)&gx[ro + p * 32];
        const uint4* gyr = (const uint4*)&gy[ro + p * 32];
        uint4 z = make_uint4(0u, 0u, 0u, 0u);
#pragma unroll
        for (int i = 0; i < 4; ++i) {
            uint4 a = ok ? gxr[i] : z;
            uint4 c = ok ? gyr[i] : z;
            *(uint4*)&Gs[row][p * 32 + i * 8] = a;
            *(uint4*)&Gs[row][128 + p * 32 + i * 8] = c;
        }
    }
    __syncthreads();
    int m = lane & 15, q = lane >> 4;
    bf16x8 afr[8];
#pragma unroll
    for (int s = 0; s < 8; ++s)
        afr[s] = *(const bf16x8*)&Gs[w * 16 + m][s * 32 + q * 8];

    for (int tt = 0; tt < 8; ++tt) {
        __syncthreads();
        {
            const uint4* sre = (const uint4*)&Wre_p[(size_t)tt * 4096];
            const uint4* sim = (const uint4*)&Wim_p[(size_t)tt * 4096];
            uint4* dre = (uint4*)&Bre[0][0][0];
            uint4* dim = (uint4*)&Bim[0][0][0];
            dre[t] = sre[t]; dre[t + 256] = sre[t + 256];
            dim[t] = sim[t]; dim[t + 256] = sim[t + 256];
        }
        __syncthreads();
        f32x4 are = {0.f, 0.f, 0.f, 0.f};
        f32x4 aim = {0.f, 0.f, 0.f, 0.f};
#pragma unroll
        for (int s = 0; s < 8; ++s) {
            bf16x8 br = *(const bf16x8*)&Bre[s][lane][0];
            bf16x8 bi = *(const bf16x8*)&Bim[s][lane][0];
            are = __builtin_amdgcn_mfma_f32_16x16x32_bf16(afr[s], br, are, 0, 0, 0);
            aim = __builtin_amdgcn_mfma_f32_16x16x32_bf16(afr[s], bi, aim, 0, 0, 0);
        }
#pragma unroll
        for (int r = 0; r < 4; ++r) {
            int row = w * 16 + q * 4 + r;
            int v = vbase + row;
            if (v < VV) {
                float gxv = bf2f(Gs[row][tt * 16 + m]);
                float gyv = bf2f(Gs[row][128 + tt * 16 + m]);
                float u = gxv * are[r] + gyv * aim[r];
                xgf[(((size_t)b * VV + v) << 7) + tt * 16 + m] = f2bf(tanh_fast(u));
            }
        }
    }
}

// ---------------- stage F: fused MLP + residual (MFMA bf16) ----------------
__global__ __launch_bounds__(256) void k_mlp(
        const float* __restrict__ x_in, const u16* __restrict__ xd,
        const u16* __restrict__ xgf,
        const u16* __restrict__ W0p, const float* __restrict__ b0,
        const u16* __restrict__ W1p, const float* __restrict__ b1,
        float* __restrict__ out) {
    __shared__ u16 Fs[64][392];     // [x_in | xd | xgf] bf16, padded stride
    __shared__ u16 Hs[64][136];     // hidden, padded stride
    __shared__ u16 Bs[12][64][8];
    int b = blockIdx.x / NT64;
    int vbase = (blockIdx.x % NT64) * 64;
    int t = threadIdx.x;
    int lane = t & 63, w = t >> 6;
    {
        int row = t >> 2, p = t & 3;
        int v = vbase + row;
        bool ok = v < VV;
        size_t ro = ((size_t)b * VV + (ok ? v : 0)) << 7;
        const float4* xir = (const float4*)&x_in[ro + p * 32];
#pragma unroll
        for (int i = 0; i < 8; ++i) {
            float4 f = ok ? xir[i] : make_float4(0.f, 0.f, 0.f, 0.f);
            uint2 u;
            u.x = pack2(f.x, f.y);
            u.y = pack2(f.z, f.w);
            *(uint2*)&Fs[row][p * 32 + i * 4] = u;
        }
        const uint4* xdr = (const uint4*)&xd[ro + p * 32];
        const uint4* xgr = (const uint4*)&xgf[ro + p * 32];
        uint4 z = make_uint4(0u, 0u, 0u, 0u);
#pragma unroll
        for (int i = 0; i < 4; ++i) {
            uint4 a = ok ? xdr[i] : z;
            uint4 c = ok ? xgr[i] : z;
            *(uint4*)&Fs[row][128 + p * 32 + i * 8] = a;
            *(uint4*)&Fs[row][256 + p * 32 + i * 8] = c;
        }
    }
    __syncthreads();
    int m = lane & 15, q = lane >> 4;
    bf16x8 af[12];
#pragma unroll
    for (int s = 0; s < 12; ++s)
        af[s] = *(const bf16x8*)&Fs[w * 16 + m][s * 32 + q * 8];

    // GEMM1: feat @ W0 + b0 -> relu -> Hs
    for (int tt = 0; tt < 8; ++tt) {
        __syncthreads();
        {
            const uint4* src = (const uint4*)&W0p[(size_t)tt * 6144];
            uint4* d = (uint4*)&Bs[0][0][0];
            d[t] = src[t];
            d[t + 256] = src[t + 256];
            d[t + 512] = src[t + 512];
        }
        __syncthreads();
        f32x4 acc = {0.f, 0.f, 0.f, 0.f};
#pragma unroll
        for (int s = 0; s < 12; ++s) {
            bf16x8 bb = *(const bf16x8*)&Bs[s][lane][0];
            acc = __builtin_amdgcn_mfma_f32_16x16x32_bf16(af[s], bb, acc, 0, 0, 0);
        }
        float bias = b0[tt * 16 + m];
#pragma unroll
        for (int r = 0; r < 4; ++r) {
            Hs[w * 16 + q * 4 + r][tt * 16 + m] = f2bf(fmaxf(acc[r] + bias, 0.f));
        }
    }

    // GEMM2: h @ W1 + b1 + x_in -> out (A-frags from own wave's Hs rows)
    bf16x8 ah[4];
    for (int tt = 0; tt < 8; ++tt) {
        __syncthreads();
        {
            const uint4* src = (const uint4*)&W1p[(size_t)tt * 2048];
            uint4* d = (uint4*)&Bs[0][0][0];
            d[t] = src[t];
        }
        if (tt == 0) {
#pragma unroll
            for (int s = 0; s < 4; ++s)
                ah[s] = *(const bf16x8*)&Hs[w * 16 + m][s * 32 + q * 8];
        }
        __syncthreads();
        f32x4 acc = {0.f, 0.f, 0.f, 0.f};
#pragma unroll
        for (int s = 0; s < 4; ++s) {
            bf16x8 bb = *(const bf16x8*)&Bs[s][lane][0];
            acc = __builtin_amdgcn_mfma_f32_16x16x32_bf16(ah[s], bb, acc, 0, 0, 0);
        }
        float bias = b1[tt * 16 + m];
#pragma unroll
        for (int r = 0; r < 4; ++r) {
            int row = w * 16 + q * 4 + r;
            int v = vbase + row;
            if (v < VV) {
                size_t off = (((size_t)b * VV + v) << 7) + tt * 16 + m;
                out[off] = acc[r] + bias + x_in[off];
            }
        }
    }
}

extern "C" void kernel_launch(void* const* d_in, const int* in_sizes, int n_in,
                              void* d_out, int out_size, void* d_ws, size_t ws_size,
                              hipStream_t stream) {
    (void)in_sizes; (void)n_in; (void)out_size; (void)ws_size;
    const float* x_in  = (const float*)d_in[0];
    const float* mass  = (const float*)d_in[1];
    const float* evals = (const float*)d_in[3];
    const float* evecs = (const float*)d_in[4];
    const int* grad_rows = (const int*)d_in[5];
    const int* grad_cols = (const int*)d_in[6];
    const float* gX = (const float*)d_in[7];
    const float* gY = (const float*)d_in[8];
    const float* dt  = (const float*)d_in[9];
    const float* Are = (const float*)d_in[10];
    const float* Aim = (const float*)d_in[11];
    const float* W0 = (const float*)d_in[12];
    const float* b0 = (const float*)d_in[13];
    const float* W1 = (const float*)d_in[14];
    const float* b1 = (const float*)d_in[15];
    float* out = (float*)d_out;

    char* w = (char*)d_ws;
    u16* xd  = (u16*)w; w += (size_t)BB * VV * CC * 2;
    u16* gx  = (u16*)w; w += (size_t)BB * VV * CC * 2;
    u16* gy  = (u16*)w; w += (size_t)BB * VV * CC * 2;
    u16* xgf = (u16*)w; w += (size_t)BB * VV * CC * 2;
    float* spec   = (float*)w; w += (size_t)BB * KK * CC * 4;
    float* spec_d = (float*)w; w += (size_t)BB * KK * CC * 4;
    int* hist   = (int*)w; w += (size_t)BB * VV * 4;
    int* rs     = (int*)w; w += (size_t)BB * VV * 4;
    int* cursor = (int*)w; w += (size_t)BB * VV * 4;
    int* csum   = (int*)w; w += (size_t)BB * 128 * 4;
    int* edge_idx = (int*)w; w += (size_t)BB * EE * 4;
    u16* Wre_p = (u16*)w; w += (size_t)4096 * 8 * 2;
    u16* Wim_p = (u16*)w; w += (size_t)4096 * 8 * 2;
    u16* W0p   = (u16*)w; w += (size_t)6144 * 8 * 2;
    u16* W1p   = (u16*)w; w += (size_t)2048 * 8 * 2;

    hipLaunchKernelGGL(k_zero_u32, dim3((BB * VV + 255) / 256), dim3(256), 0, stream,
                       (unsigned int*)hist, BB * VV);
    hipLaunchKernelGGL(k_zero_u32, dim3((BB * KK * CC + 255) / 256), dim3(256), 0, stream,
                       (unsigned int*)spec, BB * KK * CC);
    hipLaunchKernelGGL(k_hist, dim3((BB * EE + 255) / 256), dim3(256), 0, stream,
                       grad_rows, hist);
    hipLaunchKernelGGL(k_scan1, dim3(BB * NCHUNK), dim3(512), 0, stream, hist, rs, csum);
    hipLaunchKernelGGL(k_scan2, dim3(1), dim3(512), 0, stream, csum);
    hipLaunchKernelGGL(k_scan3, dim3((BB * VV + 255) / 256), dim3(256), 0, stream,
                       rs, csum, cursor);
    hipLaunchKernelGGL(k_bucket, dim3((BB * EE + 255) / 256), dim3(256), 0, stream,
                       grad_rows, cursor, edge_idx);
    hipLaunchKernelGGL(k_pack_rot, dim3(16), dim3(256), 0, stream, Are, Aim, Wre_p, Wim_p);
    hipLaunchKernelGGL(k_pack_w0, dim3(24), dim3(256), 0, stream, W0, W0p);
    hipLaunchKernelGGL(k_pack_w1, dim3(8), dim3(256), 0, stream, W1, W1p);
    hipLaunchKernelGGL(k_project, dim3(BB * PROJ_NCH), dim3(512), 0, stream,
                       x_in, mass, evecs, spec);
    hipLaunchKernelGGL(k_decay, dim3((BB * KK * CC + 255) / 256), dim3(256), 0, stream,
                       spec, evals, dt, spec_d);
    hipLaunchKernelGGL(k_unproject, dim3(BB * TILES_PER_B), dim3(256), 0, stream,
                       evecs, spec_d, xd);
    hipLaunchKernelGGL(k_rowgather, dim3(BB * VV / 4), dim3(256), 0, stream,
                       grad_cols, gX, gY, edge_idx, rs, cursor, xd, gx, gy);
    hipLaunchKernelGGL(k_gradfeat, dim3(BB * NT64), dim3(256), 0, stream,
                       gx, gy, Wre_p, Wim_p, xgf);
    hipLaunchKernelGGL(k_mlp, dim3(BB * NT64), dim3(256), 0, stream,
                       x_in, xd, xgf, W0p, b0, W1p, b1, out);
}